// Round 7
// baseline (814.567 us; speedup 1.0000x reference)
//
#include <hip/hip_runtime.h>
#include <math.h>

typedef __attribute__((ext_vector_type(8))) short short8;
typedef __attribute__((ext_vector_type(4))) float f32x4;
typedef __attribute__((ext_vector_type(16))) float f32x16;
typedef __attribute__((ext_vector_type(4))) float f4;
typedef __attribute__((ext_vector_type(4))) unsigned short us4;
typedef __attribute__((ext_vector_type(2))) unsigned int u32x2;

#define MFMA16(a,b,c) __builtin_amdgcn_mfma_f32_16x16x32_bf16(a,b,c,0,0,0)
#define MFMA32(a,b,c) __builtin_amdgcn_mfma_f32_32x32x16_bf16(a,b,c,0,0,0)

__device__ __forceinline__ unsigned short f2bf(float f) {
  unsigned int u = __float_as_uint(f);
  u = (u + 0x7FFFu + ((u >> 16) & 1u)) >> 16;   // RNE
  return (unsigned short)u;
}
__device__ __forceinline__ float bf2f(unsigned short b) {
  return __uint_as_float(((unsigned int)b) << 16);
}
// pack two f32 -> two bf16 in one u32 (round-half-up + v_perm byte select)
__device__ __forceinline__ unsigned int pk2(float a, float b) {
  unsigned int au = __float_as_uint(a) + 0x8000u;
  unsigned int bu = __float_as_uint(b) + 0x8000u;
  return __builtin_amdgcn_perm(bu, au, 0x07060302u);  // {b.hi16, a.hi16}
}

typedef const __attribute__((address_space(1))) unsigned int* gas_t;
typedef __attribute__((address_space(3))) unsigned int* las_t;
__device__ __forceinline__ void gl16(const void* g, void* l) {
  __builtin_amdgcn_global_load_lds((gas_t)g, (las_t)l, 16, 0, 0);
}

// counted vmem waits (T4): never drain to 0 in the main loop
__device__ __forceinline__ void vm_wait8() { asm volatile("s_waitcnt vmcnt(8)" ::: "memory"); }
__device__ __forceinline__ void vm_wait4() { asm volatile("s_waitcnt vmcnt(4)" ::: "memory"); }
__device__ __forceinline__ void vm_wait0() { asm volatile("s_waitcnt vmcnt(0)" ::: "memory"); }
__device__ __forceinline__ void barrier_fence() {
  __builtin_amdgcn_s_barrier();
  __builtin_amdgcn_sched_barrier(0);
}

// ---------------- f32 -> bf16 convert ----------------
__global__ void cvt_f32_bf16(const float* __restrict__ in,
                             unsigned short* __restrict__ out, int n4) {
  int i = blockIdx.x * blockDim.x + threadIdx.x;
  const int stride = gridDim.x * blockDim.x;
  for (; i < n4; i += stride) {
    f4 v = ((const f4*)in)[i];
    us4 o;
    o[0] = f2bf(v[0]); o[1] = f2bf(v[1]); o[2] = f2bf(v[2]); o[3] = f2bf(v[3]);
    ((us4*)out)[i] = o;
  }
}

// ---------------- V^T transpose: vt[h*128+d][L] <- qkv[L][3072 + h*128 + d] ----------------
__global__ __launch_bounds__(256)
void vtrans(const unsigned short* __restrict__ qkv, unsigned short* __restrict__ vt)
{
  __shared__ unsigned int tile[64][65];
  const int lb = blockIdx.x * 64;
  const int rb = blockIdx.y * 64;
  const int tid = threadIdx.x;

#pragma unroll
  for (int i = 0; i < 2; ++i) {
    int task = i * 256 + tid;
    int l = task >> 3, c = task & 7;
    short8 v = *(const short8*)(qkv + (long)(lb + l) * 4608 + 3072 + rb + c * 8);
#pragma unroll
    for (int e = 0; e < 8; ++e) tile[c * 8 + e][l] = (unsigned short)v[e];
  }
  __syncthreads();
#pragma unroll
  for (int i = 0; i < 2; ++i) {
    int task = i * 256 + tid;
    int r = task >> 3, c = task & 7;
    short8 o;
#pragma unroll
    for (int e = 0; e < 8; ++e) o[e] = (short)tile[r][c * 8 + e];
    *(short8*)(vt + (long)(rb + r) * 7040 + lb + c * 8) = o;
  }
}

// ---------------- NT GEMM: out[m][n] = sum_k A[m][k]*B[n][k] + bias[n] ----------------
template<int F32OUT>
__global__ __launch_bounds__(256)
void gemm_bt(const unsigned short* __restrict__ A,
             const unsigned short* __restrict__ B,
             const float* __restrict__ bias,
             unsigned short* __restrict__ obf,
             float* __restrict__ of32,
             int K, int ldo)
{
  const int tid = threadIdx.x;
  const int wave = tid >> 6, lane = tid & 63, lg = lane >> 4, lr = lane & 15;
  const int wr = wave >> 1, wc = wave & 1;
  const int m0 = blockIdx.y * 128, n0 = blockIdx.x * 128;

  __shared__ __align__(16) unsigned short Al[128 * 32];
  __shared__ __align__(16) unsigned short Bl[128 * 32];

  f32x4 acc[4][4];
#pragma unroll
  for (int m = 0; m < 4; ++m)
#pragma unroll
    for (int n = 0; n < 4; ++n) acc[m][n] = (f32x4){0.f, 0.f, 0.f, 0.f};

  const int r0 = tid >> 2, r1 = (tid + 256) >> 2;
  const int c0 = (tid & 3) * 8;
  const long arow0 = (long)(m0 + r0) * K, arow1 = (long)(m0 + r1) * K;
  const long brow0 = (long)(n0 + r0) * K, brow1 = (long)(n0 + r1) * K;

  for (int k0 = 0; k0 < K; k0 += 32) {
    gl16(A + arow0 + k0 + c0, (char*)Al + tid * 16);
    gl16(A + arow1 + k0 + c0, (char*)Al + (tid + 256) * 16);
    gl16(B + brow0 + k0 + c0, (char*)Bl + tid * 16);
    gl16(B + brow1 + k0 + c0, (char*)Bl + (tid + 256) * 16);
    __syncthreads();
    short8 af[4], bf[4];
#pragma unroll
    for (int m = 0; m < 4; ++m)
      af[m] = *(const short8*)(Al + (wr * 64 + m * 16 + lr) * 32 + lg * 8);
#pragma unroll
    for (int n = 0; n < 4; ++n)
      bf[n] = *(const short8*)(Bl + (wc * 64 + n * 16 + lr) * 32 + lg * 8);
#pragma unroll
    for (int m = 0; m < 4; ++m)
#pragma unroll
      for (int n = 0; n < 4; ++n)
        acc[m][n] = MFMA16(af[m], bf[n], acc[m][n]);
    __syncthreads();
  }

#pragma unroll
  for (int n = 0; n < 4; ++n) {
    const int col = n0 + wc * 64 + n * 16 + lr;
    const float bs = bias[col];
#pragma unroll
    for (int m = 0; m < 4; ++m) {
      const int row = m0 + wr * 64 + m * 16 + lg * 4;
#pragma unroll
      for (int r = 0; r < 4; ++r) {
        float v = acc[m][n][r] + bs;
        if (F32OUT) of32[(long)(row + r) * ldo + col] = v;
        else        obf[(long)(row + r) * ldo + col] = f2bf(v);
      }
    }
  }
}

// ---------------- fused RMSNorm + RoPE ----------------
__global__ __launch_bounds__(256)
void normrope(unsigned short* __restrict__ qkv, const float* __restrict__ g,
              const float* __restrict__ fc, const float* __restrict__ fs,
              int colOff, float oscale)
{
  const int l = blockIdx.x, tid = threadIdx.x;
  __shared__ float rowbuf[1536];
  __shared__ float sred[4];
  unsigned short* rp = qkv + (long)l * 4608 + colOff;

  float ss = 0.f;
  if (tid < 192) {
    short8 v = *(const short8*)(rp + tid * 8);
#pragma unroll
    for (int e = 0; e < 8; ++e) {
      float f = bf2f((unsigned short)v[e]);
      rowbuf[tid * 8 + e] = f;
      ss += f * f;
    }
  }
#pragma unroll
  for (int m = 32; m; m >>= 1) ss += __shfl_xor(ss, m, 64);
  if ((tid & 63) == 0) sred[tid >> 6] = ss;
  __syncthreads();
  const float rs = rsqrtf((sred[0] + sred[1] + sred[2] + sred[3]) * (1.f / 1536.f) + 1e-6f);

  const int f_ = l / 880, rem = l % 880, h_ = rem / 40, w_ = rem % 40;
#pragma unroll
  for (int j = 0; j < 3; ++j) {
    int p = tid + j * 256;
    int head = p >> 6, c = p & 63;
    int e = head * 128 + 2 * c;
    int tr = (c < 22) ? f_ : ((c < 43) ? h_ : w_);
    float co = fc[tr * 64 + c], si = fs[tr * 64 + c];
    float xr = rowbuf[e] * rs * g[e];
    float xi = rowbuf[e + 1] * rs * g[e + 1];
    float yr = (xr * co - xi * si) * oscale;
    float yi = (xr * si + xi * co) * oscale;
    unsigned int pk = (unsigned int)f2bf(yr) | ((unsigned int)f2bf(yi) << 16);
    *(unsigned int*)(rp + e) = pk;
  }
}

// ---------------- attention staging (256 threads, all gl16, 4 loads/thread each) ----------------
__device__ __forceinline__ void issueK(const unsigned short* __restrict__ qkv,
                                       int h, int t, int kvlen, int woff, int tid,
                                       unsigned short* Kbuf)
{
#pragma unroll
  for (int i = 0; i < 4; ++i) {
    int s = i * 256 + tid;
    int kvl = s >> 4;
    int dc = (s & 15) ^ (kvl & 7);
    int j = t * 64 + kvl; j = j < kvlen ? j : kvlen - 1;
    int gk = j + (j >= 880 ? woff : 0);
    gl16(qkv + (long)gk * 4608 + 1536 + h * 128 + dc * 8, (char*)Kbuf + s * 16);
  }
}

__device__ __forceinline__ void issueV(const unsigned short* __restrict__ vt,
                                       int h, int t, int kvlen, int woff, int tid,
                                       unsigned short* Vbuf)
{
#pragma unroll
  for (int i = 0; i < 4; ++i) {
    int s = i * 256 + tid;
    int d = s >> 3;
    int c = (s & 7) ^ (d & 7);
    int j = t * 64 + c * 8;
    j = j < kvlen ? j : kvlen - 8;
    int gk = j + (j >= 880 ? woff : 0);
    gl16(vt + (long)(h * 128 + d) * 7040 + gk, (char*)Vbuf + s * 16);
  }
}

// ---------------- chunked sink+window attention, 32x32 swapped-operand ----------------
// 1-D grid 672 (long chunks first); 4 waves x 32 q-rows; KV tile 64.
// K dbuf + V single buffer, counted-vmcnt raw-barrier schedule (48KB LDS -> 3 blocks/CU).
__global__ __launch_bounds__(256, 3)
void attn_kern(const unsigned short* __restrict__ qkv,
               const unsigned short* __restrict__ vt,
               unsigned short* __restrict__ ob)
{
  int bi = blockIdx.x, ci, rem;
  if (bi < 504) { ci = 1 + bi / 168; rem = bi % 168; }
  else          { ci = 0;            rem = bi - 504; }
  const int h = rem / 14, qt = rem % 14;

  const int tid = threadIdx.x, wave = tid >> 6, lane = tid & 63;
  const int l31 = lane & 31, hh = lane >> 5;
  const int chunk_start = ci * 1760, chunk_end = chunk_start + 1760;
  const int wstart = (ci == 0) ? 880 : ci * 1760;
  const int woff = wstart - 880;
  const int kvlen = 880 + (chunk_end - wstart);     // 1760 or 2640
  const int q0 = chunk_start + qt * 128;

  __shared__ __align__(16) unsigned short Kl[2][64 * 128];
  __shared__ __align__(16) unsigned short Vt[128 * 64];

  int qr = q0 + wave * 32 + l31;
  if (qr >= chunk_end) qr = chunk_end - 1;
  const unsigned short* qp = qkv + (long)qr * 4608 + h * 128;
  short8 qf[8];
#pragma unroll
  for (int st = 0; st < 8; ++st) qf[st] = *(const short8*)(qp + st * 16 + hh * 8);

  f32x16 Oc[4];
#pragma unroll
  for (int i = 0; i < 4; ++i)
#pragma unroll
    for (int j = 0; j < 16; ++j) Oc[i][j] = 0.f;
  float m_run = -1e30f, l_run = 0.f;
  unsigned int w0[8], w1[8];

  auto computeQK = [&](int t, int cur, f32x16* S0, f32x16* S1) {
    f32x16 a0, a1;
#pragma unroll
    for (int j = 0; j < 16; ++j) { a0[j] = 0.f; a1[j] = 0.f; }
    __builtin_amdgcn_s_setprio(1);
#pragma unroll
    for (int st = 0; st < 8; ++st) {
      int off = 32 * st + 16 * hh;
      int b0 = l31 * 256 + (off ^ ((l31 & 7) << 4));
      short8 k0 = *(const short8*)((const char*)&Kl[cur][0] + b0);
      a0 = MFMA32(k0, qf[st], a0);
      int b1 = (32 + l31) * 256 + (off ^ ((l31 & 7) << 4));
      short8 k1 = *(const short8*)((const char*)&Kl[cur][0] + b1);
      a1 = MFMA32(k1, qf[st], a1);
    }
    __builtin_amdgcn_s_setprio(0);
    if (t * 64 + 64 > kvlen) {
#pragma unroll
      for (int r = 0; r < 16; ++r) {
        int kv0 = t * 64 + (r & 3) + 8 * (r >> 2) + 4 * hh;
        if (kv0 >= kvlen)      a0[r] = -1e30f;
        if (kv0 + 32 >= kvlen) a1[r] = -1e30f;
      }
    }
    *S0 = a0; *S1 = a1;
  };

  auto finishTile = [&](f32x16& s0f, f32x16& s1f) {
    float mx[16];
#pragma unroll
    for (int r = 0; r < 16; ++r) mx[r] = fmaxf(s0f[r], s1f[r]);
#pragma unroll
    for (int w = 8; w; w >>= 1)
#pragma unroll
      for (int r = 0; r < w; ++r) mx[r] = fmaxf(mx[r], mx[r + w]);
    float pm = fmaxf(mx[0], __shfl_xor(mx[0], 32, 64));
    const bool defer = __all(pm <= m_run + 8.f);   // T13 (log2 domain)
    const float mn = defer ? m_run : fmaxf(m_run, pm);
#pragma unroll
    for (int r = 0; r < 16; ++r) {
      s0f[r] = __builtin_amdgcn_exp2f(s0f[r] - mn);
      s1f[r] = __builtin_amdgcn_exp2f(s1f[r] - mn);
    }
    float sm[16];
#pragma unroll
    for (int r = 0; r < 16; ++r) sm[r] = s0f[r] + s1f[r];
#pragma unroll
    for (int w = 8; w; w >>= 1)
#pragma unroll
      for (int r = 0; r < w; ++r) sm[r] += sm[r + w];
    float sum = sm[0] + __shfl_xor(sm[0], 32, 64);
    if (defer) {
      l_run += sum;
    } else {
      float al = __builtin_amdgcn_exp2f(m_run - mn);
      l_run = l_run * al + sum;
      m_run = mn;
#pragma unroll
      for (int i = 0; i < 4; ++i)
#pragma unroll
        for (int j = 0; j < 16; ++j) Oc[i][j] *= al;
    }
#pragma unroll
    for (int m = 0; m < 8; ++m) {
      w0[m] = pk2(s0f[2 * m], s0f[2 * m + 1]);
      w1[m] = pk2(s1f[2 * m], s1f[2 * m + 1]);
    }
  };

  auto doPV = [&]() {
    __builtin_amdgcn_s_setprio(1);
#pragma unroll
    for (int s = 0; s < 4; ++s) {
      const unsigned int* w = (s < 2) ? w0 : w1;
      const int lo4 = (s & 1) * 4;
      unsigned int x0 = __shfl_xor(w[lo4 + 2], 32, 64);
      unsigned int x1 = __shfl_xor(w[lo4 + 3], 32, 64);
      unsigned int y0 = __shfl_xor(w[lo4],     32, 64);
      unsigned int y1 = __shfl_xor(w[lo4 + 1], 32, 64);
      unsigned int fw[4];
      fw[0] = hh ? x0 : w[lo4];
      fw[1] = hh ? x1 : w[lo4 + 1];
      fw[2] = hh ? w[lo4 + 2] : y0;
      fw[3] = hh ? w[lo4 + 3] : y1;
      short8 pb = *(const short8*)fw;
#pragma unroll
      for (int dt = 0; dt < 4; ++dt) {
        int d = dt * 32 + l31;
        int byte = (d * 128 + s * 32 + hh * 16) ^ ((d & 7) << 4);
        short8 vf = *(const short8*)((const char*)&Vt[0] + byte);
        Oc[dt] = MFMA32(vf, pb, Oc[dt]);
      }
    }
    __builtin_amdgcn_s_setprio(0);
  };

  const int nt = (kvlen + 63) >> 6;

  // prologue. per-thread gl16 order: K(0)x4, K(1)x4, V(0)x4
  issueK(qkv, h, 0, kvlen, woff, tid, &Kl[0][0]);
  issueK(qkv, h, 1, kvlen, woff, tid, &Kl[1][0]);
  issueV(vt, h, 0, kvlen, woff, tid, &Vt[0]);
  vm_wait8();            // K(0) landed (K(1),V(0) in flight)
  barrier_fence();

  f32x16 sp0, sp1;
  computeQK(0, 0, &sp0, &sp1);
  barrier_fence();       // all waves done reading Kl[0] before iter-0 prefetch overwrites it

  // loop invariant at entry: outstanding = K(t+1)x4, V(t)x4 (in that order)
  for (int t = 0; t < nt - 1; ++t) {
    const int cur = t & 1;
    const bool pf2 = (t + 2 < nt);
    if (pf2) issueK(qkv, h, t + 2, kvlen, woff, tid, &Kl[cur][0]);

    if (pf2) vm_wait8(); else vm_wait4();   // K(t+1) landed; V(t)(,K(t+2)) in flight
    barrier_fence();

    f32x16 sc0, sc1;
    computeQK(t + 1, cur ^ 1, &sc0, &sc1);  // MFMA pipe
    finishTile(sp0, sp1);                   // VALU softmax overlaps

    if (pf2) vm_wait4(); else vm_wait0();   // V(t) landed; K(t+2) stays in flight
    barrier_fence();

    doPV();                                 // reads Vt
    barrier_fence();                        // all waves done reading Vt
    issueV(vt, h, t + 1, kvlen, woff, tid, &Vt[0]);
    sp0 = sc0; sp1 = sc1;
  }

  vm_wait0();             // V(nt-1) landed
  barrier_fence();
  finishTile(sp0, sp1);
  doPV();

  // --- epilogue ---
  const int qg = q0 + wave * 32 + l31;
  if (qg < chunk_end) {
    const float inv = 1.f / l_run;
    unsigned short* op = ob + (long)qg * 1536 + h * 128;
#pragma unroll
    for (int dt = 0; dt < 4; ++dt) {
#pragma unroll
      for (int gblk = 0; gblk < 4; ++gblk) {
        int d = dt * 32 + gblk * 8 + hh * 4;
        unsigned int u0 = pk2(Oc[dt][4 * gblk]     * inv, Oc[dt][4 * gblk + 1] * inv);
        unsigned int u1 = pk2(Oc[dt][4 * gblk + 2] * inv, Oc[dt][4 * gblk + 3] * inv);
        u32x2 uu; uu[0] = u0; uu[1] = u1;
        *(u32x2*)(op + d) = uu;
      }
    }
  }
}

// ---------------- launch ----------------
extern "C" void kernel_launch(void* const* d_in, const int* in_sizes, int n_in,
                              void* d_out, int out_size, void* d_ws, size_t ws_size,
                              hipStream_t stream)
{
  const float* x  = (const float*)d_in[0];
  const float* Wq = (const float*)d_in[1];
  const float* bq = (const float*)d_in[2];
  const float* Wk = (const float*)d_in[3];
  const float* bk = (const float*)d_in[4];
  const float* Wv = (const float*)d_in[5];
  const float* bv = (const float*)d_in[6];
  const float* Wo = (const float*)d_in[7];
  const float* bo = (const float*)d_in[8];
  const float* gq = (const float*)d_in[9];
  const float* gk = (const float*)d_in[10];
  const float* fc = (const float*)d_in[11];
  const float* fs = (const float*)d_in[12];

  char* ws = (char*)d_ws;
  unsigned short* xb   = (unsigned short*)(ws);               // dead after gemm0 -> reused as vt
  unsigned short* wcat = (unsigned short*)(ws + 21626880);
  unsigned short* wob  = (unsigned short*)(ws + 35782656);
  float*          bcat = (float*)(ws + 40501248);
  unsigned short* qkv  = (unsigned short*)(ws + 40519680);
  unsigned short* obuf = (unsigned short*)(ws + 105400320);
  unsigned short* vtb  = xb;                                  // V^T [1536][7040] bf16

  cvt_f32_bf16<<<2048, 256, 0, stream>>>(x,  xb,   10813440 / 4);
  cvt_f32_bf16<<<1024, 256, 0, stream>>>(Wq, wcat,            2359296 / 4);
  cvt_f32_bf16<<<1024, 256, 0, stream>>>(Wk, wcat + 2359296,  2359296 / 4);
  cvt_f32_bf16<<<1024, 256, 0, stream>>>(Wv, wcat + 4718592,  2359296 / 4);
  cvt_f32_bf16<<<1024, 256, 0, stream>>>(Wo, wob,             2359296 / 4);
  hipMemcpyAsync(bcat,        bq, 1536 * 4, hipMemcpyDeviceToDevice, stream);
  hipMemcpyAsync(bcat + 1536, bk, 1536 * 4, hipMemcpyDeviceToDevice, stream);
  hipMemcpyAsync(bcat + 3072, bv, 1536 * 4, hipMemcpyDeviceToDevice, stream);

  gemm_bt<0><<<dim3(36, 55), 256, 0, stream>>>(xb, wcat, bcat, qkv, nullptr, 1536, 4608);

  vtrans<<<dim3(110, 24), 256, 0, stream>>>(qkv, vtb);

  const float qsc = (float)(1.4426950408889634 / sqrt(128.0));
  normrope<<<7040, 256, 0, stream>>>(qkv, gq, fc, fs, 0,    qsc);
  normrope<<<7040, 256, 0, stream>>>(qkv, gk, fc, fs, 1536, 1.0f);

  attn_kern<<<672, 256, 0, stream>>>(qkv, vtb, obuf);

  gemm_bt<1><<<dim3(12, 55), 256, 0, stream>>>(obuf, wob, bo, nullptr, (float*)d_out, 1536, 1536);
}

// Round 8
// 799.048 us; speedup vs baseline: 1.0194x; 1.0194x over previous
//
#include <hip/hip_runtime.h>
#include <math.h>

typedef __attribute__((ext_vector_type(8))) short short8;
typedef __attribute__((ext_vector_type(4))) float f32x4;
typedef __attribute__((ext_vector_type(16))) float f32x16;
typedef __attribute__((ext_vector_type(4))) float f4;
typedef __attribute__((ext_vector_type(4))) unsigned short us4;
typedef __attribute__((ext_vector_type(2))) unsigned int u32x2;

#define MFMA16(a,b,c) __builtin_amdgcn_mfma_f32_16x16x32_bf16(a,b,c,0,0,0)
#define MFMA32(a,b,c) __builtin_amdgcn_mfma_f32_32x32x16_bf16(a,b,c,0,0,0)

__device__ __forceinline__ unsigned short f2bf(float f) {
  unsigned int u = __float_as_uint(f);
  u = (u + 0x7FFFu + ((u >> 16) & 1u)) >> 16;   // RNE
  return (unsigned short)u;
}
__device__ __forceinline__ float bf2f(unsigned short b) {
  return __uint_as_float(((unsigned int)b) << 16);
}
// pack two f32 -> two bf16 in one u32 (round-half-up + v_perm byte select)
__device__ __forceinline__ unsigned int pk2(float a, float b) {
  unsigned int au = __float_as_uint(a) + 0x8000u;
  unsigned int bu = __float_as_uint(b) + 0x8000u;
  return __builtin_amdgcn_perm(bu, au, 0x07060302u);  // {b.hi16, a.hi16}
}

typedef const __attribute__((address_space(1))) unsigned int* gas_t;
typedef __attribute__((address_space(3))) unsigned int* las_t;
__device__ __forceinline__ void gl16(const void* g, void* l) {
  __builtin_amdgcn_global_load_lds((gas_t)g, (las_t)l, 16, 0, 0);
}

// counted vmem waits (T4): never drain to 0 in the main loop
__device__ __forceinline__ void vm_wait8() { asm volatile("s_waitcnt vmcnt(8)" ::: "memory"); }
__device__ __forceinline__ void vm_wait4() { asm volatile("s_waitcnt vmcnt(4)" ::: "memory"); }
__device__ __forceinline__ void vm_wait0() { asm volatile("s_waitcnt vmcnt(0)" ::: "memory"); }
__device__ __forceinline__ void barrier_fence() {
  __builtin_amdgcn_s_barrier();
  __builtin_amdgcn_sched_barrier(0);
}

// ---------------- f32 -> bf16 convert ----------------
__global__ void cvt_f32_bf16(const float* __restrict__ in,
                             unsigned short* __restrict__ out, int n4) {
  int i = blockIdx.x * blockDim.x + threadIdx.x;
  const int stride = gridDim.x * blockDim.x;
  for (; i < n4; i += stride) {
    f4 v = ((const f4*)in)[i];
    us4 o;
    o[0] = f2bf(v[0]); o[1] = f2bf(v[1]); o[2] = f2bf(v[2]); o[3] = f2bf(v[3]);
    ((us4*)out)[i] = o;
  }
}

// ---------------- V^T transpose: vt[h*128+d][L] <- qkv[L][3072 + h*128 + d] ----------------
__global__ __launch_bounds__(256)
void vtrans(const unsigned short* __restrict__ qkv, unsigned short* __restrict__ vt)
{
  __shared__ unsigned int tile[64][65];
  const int lb = blockIdx.x * 64;
  const int rb = blockIdx.y * 64;
  const int tid = threadIdx.x;

#pragma unroll
  for (int i = 0; i < 2; ++i) {
    int task = i * 256 + tid;
    int l = task >> 3, c = task & 7;
    short8 v = *(const short8*)(qkv + (long)(lb + l) * 4608 + 3072 + rb + c * 8);
#pragma unroll
    for (int e = 0; e < 8; ++e) tile[c * 8 + e][l] = (unsigned short)v[e];
  }
  __syncthreads();
#pragma unroll
  for (int i = 0; i < 2; ++i) {
    int task = i * 256 + tid;
    int r = task >> 3, c = task & 7;
    short8 o;
#pragma unroll
    for (int e = 0; e < 8; ++e) o[e] = (short)tile[r][c * 8 + e];
    *(short8*)(vt + (long)(rb + r) * 7040 + lb + c * 8) = o;
  }
}

// ---------------- NT GEMM: out[m][n] = sum_k A[m][k]*B[n][k] + bias[n] ----------------
template<int F32OUT>
__global__ __launch_bounds__(256)
void gemm_bt(const unsigned short* __restrict__ A,
             const unsigned short* __restrict__ B,
             const float* __restrict__ bias,
             unsigned short* __restrict__ obf,
             float* __restrict__ of32,
             int K, int ldo)
{
  const int tid = threadIdx.x;
  const int wave = tid >> 6, lane = tid & 63, lg = lane >> 4, lr = lane & 15;
  const int wr = wave >> 1, wc = wave & 1;
  const int m0 = blockIdx.y * 128, n0 = blockIdx.x * 128;

  __shared__ __align__(16) unsigned short Al[128 * 32];
  __shared__ __align__(16) unsigned short Bl[128 * 32];

  f32x4 acc[4][4];
#pragma unroll
  for (int m = 0; m < 4; ++m)
#pragma unroll
    for (int n = 0; n < 4; ++n) acc[m][n] = (f32x4){0.f, 0.f, 0.f, 0.f};

  const int r0 = tid >> 2, r1 = (tid + 256) >> 2;
  const int c0 = (tid & 3) * 8;
  const long arow0 = (long)(m0 + r0) * K, arow1 = (long)(m0 + r1) * K;
  const long brow0 = (long)(n0 + r0) * K, brow1 = (long)(n0 + r1) * K;

  for (int k0 = 0; k0 < K; k0 += 32) {
    gl16(A + arow0 + k0 + c0, (char*)Al + tid * 16);
    gl16(A + arow1 + k0 + c0, (char*)Al + (tid + 256) * 16);
    gl16(B + brow0 + k0 + c0, (char*)Bl + tid * 16);
    gl16(B + brow1 + k0 + c0, (char*)Bl + (tid + 256) * 16);
    __syncthreads();
    short8 af[4], bf[4];
#pragma unroll
    for (int m = 0; m < 4; ++m)
      af[m] = *(const short8*)(Al + (wr * 64 + m * 16 + lr) * 32 + lg * 8);
#pragma unroll
    for (int n = 0; n < 4; ++n)
      bf[n] = *(const short8*)(Bl + (wc * 64 + n * 16 + lr) * 32 + lg * 8);
#pragma unroll
    for (int m = 0; m < 4; ++m)
#pragma unroll
      for (int n = 0; n < 4; ++n)
        acc[m][n] = MFMA16(af[m], bf[n], acc[m][n]);
    __syncthreads();
  }

#pragma unroll
  for (int n = 0; n < 4; ++n) {
    const int col = n0 + wc * 64 + n * 16 + lr;
    const float bs = bias[col];
#pragma unroll
    for (int m = 0; m < 4; ++m) {
      const int row = m0 + wr * 64 + m * 16 + lg * 4;
#pragma unroll
      for (int r = 0; r < 4; ++r) {
        float v = acc[m][n][r] + bs;
        if (F32OUT) of32[(long)(row + r) * ldo + col] = v;
        else        obf[(long)(row + r) * ldo + col] = f2bf(v);
      }
    }
  }
}

// ---------------- fused RMSNorm + RoPE ----------------
__global__ __launch_bounds__(256)
void normrope(unsigned short* __restrict__ qkv, const float* __restrict__ g,
              const float* __restrict__ fc, const float* __restrict__ fs,
              int colOff, float oscale)
{
  const int l = blockIdx.x, tid = threadIdx.x;
  __shared__ float rowbuf[1536];
  __shared__ float sred[4];
  unsigned short* rp = qkv + (long)l * 4608 + colOff;

  float ss = 0.f;
  if (tid < 192) {
    short8 v = *(const short8*)(rp + tid * 8);
#pragma unroll
    for (int e = 0; e < 8; ++e) {
      float f = bf2f((unsigned short)v[e]);
      rowbuf[tid * 8 + e] = f;
      ss += f * f;
    }
  }
#pragma unroll
  for (int m = 32; m; m >>= 1) ss += __shfl_xor(ss, m, 64);
  if ((tid & 63) == 0) sred[tid >> 6] = ss;
  __syncthreads();
  const float rs = rsqrtf((sred[0] + sred[1] + sred[2] + sred[3]) * (1.f / 1536.f) + 1e-6f);

  const int f_ = l / 880, rem = l % 880, h_ = rem / 40, w_ = rem % 40;
#pragma unroll
  for (int j = 0; j < 3; ++j) {
    int p = tid + j * 256;
    int head = p >> 6, c = p & 63;
    int e = head * 128 + 2 * c;
    int tr = (c < 22) ? f_ : ((c < 43) ? h_ : w_);
    float co = fc[tr * 64 + c], si = fs[tr * 64 + c];
    float xr = rowbuf[e] * rs * g[e];
    float xi = rowbuf[e + 1] * rs * g[e + 1];
    float yr = (xr * co - xi * si) * oscale;
    float yi = (xr * si + xi * co) * oscale;
    unsigned int pk = (unsigned int)f2bf(yr) | ((unsigned int)f2bf(yi) << 16);
    *(unsigned int*)(rp + e) = pk;
  }
}

// ---------------- attention staging (256 threads, all gl16, 4 loads/thread each) ----------------
__device__ __forceinline__ void issueK(const unsigned short* __restrict__ qkv,
                                       int h, int t, int kvlen, int woff, int tid,
                                       unsigned short* Kbuf)
{
#pragma unroll
  for (int i = 0; i < 4; ++i) {
    int s = i * 256 + tid;
    int kvl = s >> 4;
    int dc = (s & 15) ^ (kvl & 7);
    int j = t * 64 + kvl; j = j < kvlen ? j : kvlen - 1;
    int gk = j + (j >= 880 ? woff : 0);
    gl16(qkv + (long)gk * 4608 + 1536 + h * 128 + dc * 8, (char*)Kbuf + s * 16);
  }
}

__device__ __forceinline__ void issueV(const unsigned short* __restrict__ vt,
                                       int h, int t, int kvlen, int woff, int tid,
                                       unsigned short* Vbuf)
{
#pragma unroll
  for (int i = 0; i < 4; ++i) {
    int s = i * 256 + tid;
    int d = s >> 3;
    int c = (s & 7) ^ (d & 7);
    int j = t * 64 + c * 8;
    j = j < kvlen ? j : kvlen - 8;
    int gk = j + (j >= 880 ? woff : 0);
    gl16(vt + (long)(h * 128 + d) * 7040 + gk, (char*)Vbuf + s * 16);
  }
}

// ---------------- chunked sink+window attention, 32x32 swapped-operand ----------------
// 1-D grid 672 = 48 KV-streams (ci,h) x 14 q-tiles. Stream-aware XCD swizzle:
// all 14 blocks sharing a KV stream land on the same XCD (bi&7) so the stream
// is fetched to that XCD's L2 once. Whole grid co-resident (48KB LDS, 3 blk/CU).
__global__ __launch_bounds__(256, 3)
void attn_kern(const unsigned short* __restrict__ qkv,
               const unsigned short* __restrict__ vt,
               unsigned short* __restrict__ ob)
{
  const int bi = blockIdx.x;
  const int xcd = bi & 7;
  const int slot = bi >> 3;            // 0..83
  const int sid = (slot / 14) * 8 + xcd;  // stream id 0..47
  const int qt = slot % 14;
  const int ci = sid / 12, h = sid % 12;

  const int tid = threadIdx.x, wave = tid >> 6, lane = tid & 63;
  const int l31 = lane & 31, hh = lane >> 5;
  const int chunk_start = ci * 1760, chunk_end = chunk_start + 1760;
  const int wstart = (ci == 0) ? 880 : ci * 1760;
  const int woff = wstart - 880;
  const int kvlen = 880 + (chunk_end - wstart);     // 1760 or 2640
  const int q0 = chunk_start + qt * 128;

  __shared__ __align__(16) unsigned short Kl[2][64 * 128];
  __shared__ __align__(16) unsigned short Vt[128 * 64];

  int qr = q0 + wave * 32 + l31;
  if (qr >= chunk_end) qr = chunk_end - 1;
  const unsigned short* qp = qkv + (long)qr * 4608 + h * 128;
  short8 qf[8];
#pragma unroll
  for (int st = 0; st < 8; ++st) qf[st] = *(const short8*)(qp + st * 16 + hh * 8);

  f32x16 Oc[4];
#pragma unroll
  for (int i = 0; i < 4; ++i)
#pragma unroll
    for (int j = 0; j < 16; ++j) Oc[i][j] = 0.f;
  float m_run = -1e30f, l_run = 0.f;
  unsigned int w0[8], w1[8];

  auto computeQK = [&](int t, int cur, f32x16* S0, f32x16* S1) {
    f32x16 a0, a1;
#pragma unroll
    for (int j = 0; j < 16; ++j) { a0[j] = 0.f; a1[j] = 0.f; }
    __builtin_amdgcn_s_setprio(1);
#pragma unroll
    for (int st = 0; st < 8; ++st) {
      int off = 32 * st + 16 * hh;
      int b0 = l31 * 256 + (off ^ ((l31 & 7) << 4));
      short8 k0 = *(const short8*)((const char*)&Kl[cur][0] + b0);
      a0 = MFMA32(k0, qf[st], a0);
      int b1 = (32 + l31) * 256 + (off ^ ((l31 & 7) << 4));
      short8 k1 = *(const short8*)((const char*)&Kl[cur][0] + b1);
      a1 = MFMA32(k1, qf[st], a1);
    }
    __builtin_amdgcn_s_setprio(0);
    if (t * 64 + 64 > kvlen) {
#pragma unroll
      for (int r = 0; r < 16; ++r) {
        int kv0 = t * 64 + (r & 3) + 8 * (r >> 2) + 4 * hh;
        if (kv0 >= kvlen)      a0[r] = -1e30f;
        if (kv0 + 32 >= kvlen) a1[r] = -1e30f;
      }
    }
    *S0 = a0; *S1 = a1;
  };

  auto finishTile = [&](f32x16& s0f, f32x16& s1f) {
    float mx[16];
#pragma unroll
    for (int r = 0; r < 16; ++r) mx[r] = fmaxf(s0f[r], s1f[r]);
#pragma unroll
    for (int w = 8; w; w >>= 1)
#pragma unroll
      for (int r = 0; r < w; ++r) mx[r] = fmaxf(mx[r], mx[r + w]);
    float pm = fmaxf(mx[0], __shfl_xor(mx[0], 32, 64));
    const bool defer = __all(pm <= m_run + 8.f);   // T13 (log2 domain)
    const float mn = defer ? m_run : fmaxf(m_run, pm);
#pragma unroll
    for (int r = 0; r < 16; ++r) {
      s0f[r] = __builtin_amdgcn_exp2f(s0f[r] - mn);
      s1f[r] = __builtin_amdgcn_exp2f(s1f[r] - mn);
    }
    float sm[16];
#pragma unroll
    for (int r = 0; r < 16; ++r) sm[r] = s0f[r] + s1f[r];
#pragma unroll
    for (int w = 8; w; w >>= 1)
#pragma unroll
      for (int r = 0; r < w; ++r) sm[r] += sm[r + w];
    float sum = sm[0] + __shfl_xor(sm[0], 32, 64);
    if (defer) {
      l_run += sum;
    } else {
      float al = __builtin_amdgcn_exp2f(m_run - mn);
      l_run = l_run * al + sum;
      m_run = mn;
#pragma unroll
      for (int i = 0; i < 4; ++i)
#pragma unroll
        for (int j = 0; j < 16; ++j) Oc[i][j] *= al;
    }
#pragma unroll
    for (int m = 0; m < 8; ++m) {
      w0[m] = pk2(s0f[2 * m], s0f[2 * m + 1]);
      w1[m] = pk2(s1f[2 * m], s1f[2 * m + 1]);
    }
  };

  auto doPV = [&]() {
    __builtin_amdgcn_s_setprio(1);
#pragma unroll
    for (int s = 0; s < 4; ++s) {
      const unsigned int* w = (s < 2) ? w0 : w1;
      const int lo4 = (s & 1) * 4;
      unsigned int x0 = __shfl_xor(w[lo4 + 2], 32, 64);
      unsigned int x1 = __shfl_xor(w[lo4 + 3], 32, 64);
      unsigned int y0 = __shfl_xor(w[lo4],     32, 64);
      unsigned int y1 = __shfl_xor(w[lo4 + 1], 32, 64);
      unsigned int fw[4];
      fw[0] = hh ? x0 : w[lo4];
      fw[1] = hh ? x1 : w[lo4 + 1];
      fw[2] = hh ? w[lo4 + 2] : y0;
      fw[3] = hh ? w[lo4 + 3] : y1;
      short8 pb = *(const short8*)fw;
#pragma unroll
      for (int dt = 0; dt < 4; ++dt) {
        int d = dt * 32 + l31;
        int byte = (d * 128 + s * 32 + hh * 16) ^ ((d & 7) << 4);
        short8 vf = *(const short8*)((const char*)&Vt[0] + byte);
        Oc[dt] = MFMA32(vf, pb, Oc[dt]);
      }
    }
    __builtin_amdgcn_s_setprio(0);
  };

  const int nt = (kvlen + 63) >> 6;

  // prologue. per-thread gl16 order: K(0)x4, K(1)x4, V(0)x4
  issueK(qkv, h, 0, kvlen, woff, tid, &Kl[0][0]);
  issueK(qkv, h, 1, kvlen, woff, tid, &Kl[1][0]);
  issueV(vt, h, 0, kvlen, woff, tid, &Vt[0]);
  vm_wait8();            // K(0) landed (K(1),V(0) in flight)
  barrier_fence();

  f32x16 sp0, sp1;
  computeQK(0, 0, &sp0, &sp1);
  barrier_fence();       // all waves done reading Kl[0] before iter-0 prefetch overwrites it

  // loop invariant at entry: outstanding = K(t+1)x4, V(t)x4 (in that order)
  for (int t = 0; t < nt - 1; ++t) {
    const int cur = t & 1;
    const bool pf2 = (t + 2 < nt);
    if (pf2) issueK(qkv, h, t + 2, kvlen, woff, tid, &Kl[cur][0]);

    if (pf2) vm_wait8(); else vm_wait4();   // K(t+1) landed; V(t)(,K(t+2)) in flight
    barrier_fence();

    f32x16 sc0, sc1;
    computeQK(t + 1, cur ^ 1, &sc0, &sc1);  // MFMA pipe
    finishTile(sp0, sp1);                   // VALU softmax overlaps

    if (pf2) vm_wait4(); else vm_wait0();   // V(t) landed; K(t+2) stays in flight
    barrier_fence();

    doPV();                                 // reads Vt
    barrier_fence();                        // all waves done reading Vt
    issueV(vt, h, t + 1, kvlen, woff, tid, &Vt[0]);
    sp0 = sc0; sp1 = sc1;
  }

  vm_wait0();             // V(nt-1) landed
  barrier_fence();
  finishTile(sp0, sp1);
  doPV();

  // --- epilogue ---
  const int qg = q0 + wave * 32 + l31;
  if (qg < chunk_end) {
    const float inv = 1.f / l_run;
    unsigned short* op = ob + (long)qg * 1536 + h * 128;
#pragma unroll
    for (int dt = 0; dt < 4; ++dt) {
#pragma unroll
      for (int gblk = 0; gblk < 4; ++gblk) {
        int d = dt * 32 + gblk * 8 + hh * 4;
        unsigned int u0 = pk2(Oc[dt][4 * gblk]     * inv, Oc[dt][4 * gblk + 1] * inv);
        unsigned int u1 = pk2(Oc[dt][4 * gblk + 2] * inv, Oc[dt][4 * gblk + 3] * inv);
        u32x2 uu; uu[0] = u0; uu[1] = u1;
        *(u32x2*)(op + d) = uu;
      }
    }
  }
}

// ---------------- launch ----------------
extern "C" void kernel_launch(void* const* d_in, const int* in_sizes, int n_in,
                              void* d_out, int out_size, void* d_ws, size_t ws_size,
                              hipStream_t stream)
{
  const float* x  = (const float*)d_in[0];
  const float* Wq = (const float*)d_in[1];
  const float* bq = (const float*)d_in[2];
  const float* Wk = (const float*)d_in[3];
  const float* bk = (const float*)d_in[4];
  const float* Wv = (const float*)d_in[5];
  const float* bv = (const float*)d_in[6];
  const float* Wo = (const float*)d_in[7];
  const float* bo = (const float*)d_in[8];
  const float* gq = (const float*)d_in[9];
  const float* gk = (const float*)d_in[10];
  const float* fc = (const float*)d_in[11];
  const float* fs = (const float*)d_in[12];

  char* ws = (char*)d_ws;
  unsigned short* xb   = (unsigned short*)(ws);               // dead after gemm0 -> reused as vt
  unsigned short* wcat = (unsigned short*)(ws + 21626880);
  unsigned short* wob  = (unsigned short*)(ws + 35782656);
  float*          bcat = (float*)(ws + 40501248);
  unsigned short* qkv  = (unsigned short*)(ws + 40519680);
  unsigned short* obuf = (unsigned short*)(ws + 105400320);
  unsigned short* vtb  = xb;                                  // V^T [1536][7040] bf16

  cvt_f32_bf16<<<2048, 256, 0, stream>>>(x,  xb,   10813440 / 4);
  cvt_f32_bf16<<<1024, 256, 0, stream>>>(Wq, wcat,            2359296 / 4);
  cvt_f32_bf16<<<1024, 256, 0, stream>>>(Wk, wcat + 2359296,  2359296 / 4);
  cvt_f32_bf16<<<1024, 256, 0, stream>>>(Wv, wcat + 4718592,  2359296 / 4);
  cvt_f32_bf16<<<1024, 256, 0, stream>>>(Wo, wob,             2359296 / 4);
  hipMemcpyAsync(bcat,        bq, 1536 * 4, hipMemcpyDeviceToDevice, stream);
  hipMemcpyAsync(bcat + 1536, bk, 1536 * 4, hipMemcpyDeviceToDevice, stream);
  hipMemcpyAsync(bcat + 3072, bv, 1536 * 4, hipMemcpyDeviceToDevice, stream);

  gemm_bt<0><<<dim3(36, 55), 256, 0, stream>>>(xb, wcat, bcat, qkv, nullptr, 1536, 4608);

  vtrans<<<dim3(110, 24), 256, 0, stream>>>(qkv, vtb);

  const float qsc = (float)(1.4426950408889634 / sqrt(128.0));
  normrope<<<7040, 256, 0, stream>>>(qkv, gq, fc, fs, 0,    qsc);
  normrope<<<7040, 256, 0, stream>>>(qkv, gk, fc, fs, 1536, 1.0f);

  attn_kern<<<672, 256, 0, stream>>>(qkv, vtb, obuf);

  gemm_bt<1><<<dim3(12, 55), 256, 0, stream>>>(obuf, wob, bo, nullptr, (float*)d_out, 1536, 1536);
}

// Round 9
// 746.329 us; speedup vs baseline: 1.0914x; 1.0706x over previous
//
#include <hip/hip_runtime.h>
#include <math.h>

typedef __attribute__((ext_vector_type(8))) short short8;
typedef __attribute__((ext_vector_type(4))) float f32x4;
typedef __attribute__((ext_vector_type(16))) float f32x16;
typedef __attribute__((ext_vector_type(4))) float f4;
typedef __attribute__((ext_vector_type(4))) unsigned short us4;
typedef __attribute__((ext_vector_type(2))) unsigned int u32x2;

#define MFMA16(a,b,c) __builtin_amdgcn_mfma_f32_16x16x32_bf16(a,b,c,0,0,0)
#define MFMA32(a,b,c) __builtin_amdgcn_mfma_f32_32x32x16_bf16(a,b,c,0,0,0)

__device__ __forceinline__ unsigned short f2bf(float f) {
  unsigned int u = __float_as_uint(f);
  u = (u + 0x7FFFu + ((u >> 16) & 1u)) >> 16;   // RNE
  return (unsigned short)u;
}
__device__ __forceinline__ float bf2f(unsigned short b) {
  return __uint_as_float(((unsigned int)b) << 16);
}
// pack two f32 -> two bf16 in one u32 (round-half-up + v_perm byte select)
__device__ __forceinline__ unsigned int pk2(float a, float b) {
  unsigned int au = __float_as_uint(a) + 0x8000u;
  unsigned int bu = __float_as_uint(b) + 0x8000u;
  return __builtin_amdgcn_perm(bu, au, 0x07060302u);  // {b.hi16, a.hi16}
}

typedef const __attribute__((address_space(1))) unsigned int* gas_t;
typedef __attribute__((address_space(3))) unsigned int* las_t;
__device__ __forceinline__ void gl16(const void* g, void* l) {
  __builtin_amdgcn_global_load_lds((gas_t)g, (las_t)l, 16, 0, 0);
}

// ---------------- f32 -> bf16 convert ----------------
__global__ void cvt_f32_bf16(const float* __restrict__ in,
                             unsigned short* __restrict__ out, int n4) {
  int i = blockIdx.x * blockDim.x + threadIdx.x;
  const int stride = gridDim.x * blockDim.x;
  for (; i < n4; i += stride) {
    f4 v = ((const f4*)in)[i];
    us4 o;
    o[0] = f2bf(v[0]); o[1] = f2bf(v[1]); o[2] = f2bf(v[2]); o[3] = f2bf(v[3]);
    ((us4*)out)[i] = o;
  }
}

// ---------------- V^T transpose: vt[h*128+d][L] <- qkv[L][3072 + h*128 + d] ----------------
__global__ __launch_bounds__(256)
void vtrans(const unsigned short* __restrict__ qkv, unsigned short* __restrict__ vt)
{
  __shared__ unsigned int tile[64][65];
  const int lb = blockIdx.x * 64;
  const int rb = blockIdx.y * 64;
  const int tid = threadIdx.x;

#pragma unroll
  for (int i = 0; i < 2; ++i) {
    int task = i * 256 + tid;
    int l = task >> 3, c = task & 7;
    short8 v = *(const short8*)(qkv + (long)(lb + l) * 4608 + 3072 + rb + c * 8);
#pragma unroll
    for (int e = 0; e < 8; ++e) tile[c * 8 + e][l] = (unsigned short)v[e];
  }
  __syncthreads();
#pragma unroll
  for (int i = 0; i < 2; ++i) {
    int task = i * 256 + tid;
    int r = task >> 3, c = task & 7;
    short8 o;
#pragma unroll
    for (int e = 0; e < 8; ++e) o[e] = (short)tile[r][c * 8 + e];
    *(short8*)(vt + (long)(rb + r) * 7040 + lb + c * 8) = o;
  }
}

// ---------------- NT GEMM: out[m][n] = sum_k A[m][k]*B[n][k] + bias[n] ----------------
template<int F32OUT>
__global__ __launch_bounds__(256)
void gemm_bt(const unsigned short* __restrict__ A,
             const unsigned short* __restrict__ B,
             const float* __restrict__ bias,
             unsigned short* __restrict__ obf,
             float* __restrict__ of32,
             int K, int ldo)
{
  const int tid = threadIdx.x;
  const int wave = tid >> 6, lane = tid & 63, lg = lane >> 4, lr = lane & 15;
  const int wr = wave >> 1, wc = wave & 1;
  const int m0 = blockIdx.y * 128, n0 = blockIdx.x * 128;

  __shared__ __align__(16) unsigned short Al[128 * 32];
  __shared__ __align__(16) unsigned short Bl[128 * 32];

  f32x4 acc[4][4];
#pragma unroll
  for (int m = 0; m < 4; ++m)
#pragma unroll
    for (int n = 0; n < 4; ++n) acc[m][n] = (f32x4){0.f, 0.f, 0.f, 0.f};

  const int r0 = tid >> 2, r1 = (tid + 256) >> 2;
  const int c0 = (tid & 3) * 8;
  const long arow0 = (long)(m0 + r0) * K, arow1 = (long)(m0 + r1) * K;
  const long brow0 = (long)(n0 + r0) * K, brow1 = (long)(n0 + r1) * K;

  for (int k0 = 0; k0 < K; k0 += 32) {
    gl16(A + arow0 + k0 + c0, (char*)Al + tid * 16);
    gl16(A + arow1 + k0 + c0, (char*)Al + (tid + 256) * 16);
    gl16(B + brow0 + k0 + c0, (char*)Bl + tid * 16);
    gl16(B + brow1 + k0 + c0, (char*)Bl + (tid + 256) * 16);
    __syncthreads();
    short8 af[4], bf[4];
#pragma unroll
    for (int m = 0; m < 4; ++m)
      af[m] = *(const short8*)(Al + (wr * 64 + m * 16 + lr) * 32 + lg * 8);
#pragma unroll
    for (int n = 0; n < 4; ++n)
      bf[n] = *(const short8*)(Bl + (wc * 64 + n * 16 + lr) * 32 + lg * 8);
#pragma unroll
    for (int m = 0; m < 4; ++m)
#pragma unroll
      for (int n = 0; n < 4; ++n)
        acc[m][n] = MFMA16(af[m], bf[n], acc[m][n]);
    __syncthreads();
  }

#pragma unroll
  for (int n = 0; n < 4; ++n) {
    const int col = n0 + wc * 64 + n * 16 + lr;
    const float bs = bias[col];
#pragma unroll
    for (int m = 0; m < 4; ++m) {
      const int row = m0 + wr * 64 + m * 16 + lg * 4;
#pragma unroll
      for (int r = 0; r < 4; ++r) {
        float v = acc[m][n][r] + bs;
        if (F32OUT) of32[(long)(row + r) * ldo + col] = v;
        else        obf[(long)(row + r) * ldo + col] = f2bf(v);
      }
    }
  }
}

// ---------------- fused RMSNorm + RoPE ----------------
__global__ __launch_bounds__(256)
void normrope(unsigned short* __restrict__ qkv, const float* __restrict__ g,
              const float* __restrict__ fc, const float* __restrict__ fs,
              int colOff, float oscale)
{
  const int l = blockIdx.x, tid = threadIdx.x;
  __shared__ float rowbuf[1536];
  __shared__ float sred[4];
  unsigned short* rp = qkv + (long)l * 4608 + colOff;

  float ss = 0.f;
  if (tid < 192) {
    short8 v = *(const short8*)(rp + tid * 8);
#pragma unroll
    for (int e = 0; e < 8; ++e) {
      float f = bf2f((unsigned short)v[e]);
      rowbuf[tid * 8 + e] = f;
      ss += f * f;
    }
  }
#pragma unroll
  for (int m = 32; m; m >>= 1) ss += __shfl_xor(ss, m, 64);
  if ((tid & 63) == 0) sred[tid >> 6] = ss;
  __syncthreads();
  const float rs = rsqrtf((sred[0] + sred[1] + sred[2] + sred[3]) * (1.f / 1536.f) + 1e-6f);

  const int f_ = l / 880, rem = l % 880, h_ = rem / 40, w_ = rem % 40;
#pragma unroll
  for (int j = 0; j < 3; ++j) {
    int p = tid + j * 256;
    int head = p >> 6, c = p & 63;
    int e = head * 128 + 2 * c;
    int tr = (c < 22) ? f_ : ((c < 43) ? h_ : w_);
    float co = fc[tr * 64 + c], si = fs[tr * 64 + c];
    float xr = rowbuf[e] * rs * g[e];
    float xi = rowbuf[e + 1] * rs * g[e + 1];
    float yr = (xr * co - xi * si) * oscale;
    float yi = (xr * si + xi * co) * oscale;
    unsigned int pk = (unsigned int)f2bf(yr) | ((unsigned int)f2bf(yi) << 16);
    *(unsigned int*)(rp + e) = pk;
  }
}

// ---------------- attention staging (512 threads, all gl16, 2 loads/thread each) ----------------
// K tile: Kl[kv][128d], linear dest, inverse-swizzled source -> reads use ^((kv&7)<<4)
__device__ __forceinline__ void issueK(const unsigned short* __restrict__ qkv,
                                       int h, int t, int kvlen, int woff, int tid,
                                       unsigned short* Kbuf)
{
#pragma unroll
  for (int i = 0; i < 2; ++i) {
    int s = i * 512 + tid;
    int kvl = s >> 4;
    int dc = (s & 15) ^ (kvl & 7);
    int j = t * 64 + kvl; j = j < kvlen ? j : kvlen - 1;
    int gk = j + (j >= 880 ? woff : 0);
    gl16(qkv + (long)gk * 4608 + 1536 + h * 128 + dc * 8, (char*)Kbuf + s * 16);
  }
}

// V^T tile: Vt[d][64kv] from pre-transposed vt; linear dest, inverse-swizzled
// source kv-chunk -> reads use ^((d&7)<<4).
__device__ __forceinline__ void issueV(const unsigned short* __restrict__ vt,
                                       int h, int t, int kvlen, int woff, int tid,
                                       unsigned short* Vbuf)
{
#pragma unroll
  for (int i = 0; i < 2; ++i) {
    int s = i * 512 + tid;
    int d = s >> 3;
    int c = (s & 7) ^ (d & 7);
    int j = t * 64 + c * 8;
    j = j < kvlen ? j : kvlen - 8;
    int gk = j + (j >= 880 ? woff : 0);
    gl16(vt + (long)(h * 128 + d) * 7040 + gk, (char*)Vbuf + s * 16);
  }
}

// ---------------- chunked sink+window attention, 32x32 swapped-operand ----------------
// grid (7 qtiles, 4 chunks, 12 heads); 8 waves x 32 q-rows = 256 q/block; KV tile 64.
// 2 waves/SIMD inside the block cover each other's softmax/MFMA phases; K,V dbuf gl16.
__global__ __launch_bounds__(512, 4)
void attn_kern(const unsigned short* __restrict__ qkv,
               const unsigned short* __restrict__ vt,
               unsigned short* __restrict__ ob)
{
  const int qt = blockIdx.x, ci = blockIdx.y, h = blockIdx.z;
  const int tid = threadIdx.x, wave = tid >> 6, lane = tid & 63;
  const int l31 = lane & 31, hh = lane >> 5;
  const int chunk_start = ci * 1760, chunk_end = chunk_start + 1760;
  const int wstart = (ci == 0) ? 880 : ci * 1760;
  const int woff = wstart - 880;
  const int kvlen = 880 + (chunk_end - wstart);     // 1760 or 2640
  const int q0 = chunk_start + qt * 256;

  __shared__ __align__(16) unsigned short Kl[2][64 * 128];
  __shared__ __align__(16) unsigned short Vt[2][128 * 64];

  int qr = q0 + wave * 32 + l31;
  if (qr >= chunk_end) qr = chunk_end - 1;
  const unsigned short* qp = qkv + (long)qr * 4608 + h * 128;
  short8 qf[8];
#pragma unroll
  for (int st = 0; st < 8; ++st) qf[st] = *(const short8*)(qp + st * 16 + hh * 8);

  f32x16 Oc[4];
#pragma unroll
  for (int i = 0; i < 4; ++i)
#pragma unroll
    for (int j = 0; j < 16; ++j) Oc[i][j] = 0.f;
  float m_run = -1e30f, l_run = 0.f;
  unsigned int w0[8], w1[8];

  auto computeQK = [&](int t, int cur, f32x16& a0, f32x16& a1) {
#pragma unroll
    for (int j = 0; j < 16; ++j) { a0[j] = 0.f; a1[j] = 0.f; }
    __builtin_amdgcn_s_setprio(1);
#pragma unroll
    for (int st = 0; st < 8; ++st) {
      int off = 32 * st + 16 * hh;
      int b0 = l31 * 256 + (off ^ ((l31 & 7) << 4));
      short8 k0 = *(const short8*)((const char*)&Kl[cur][0] + b0);
      a0 = MFMA32(k0, qf[st], a0);
      int b1 = (32 + l31) * 256 + (off ^ ((l31 & 7) << 4));
      short8 k1 = *(const short8*)((const char*)&Kl[cur][0] + b1);
      a1 = MFMA32(k1, qf[st], a1);
    }
    __builtin_amdgcn_s_setprio(0);
    if (t * 64 + 64 > kvlen) {       // uniform: tail tile only
#pragma unroll
      for (int r = 0; r < 16; ++r) {
        int kv0 = t * 64 + (r & 3) + 8 * (r >> 2) + 4 * hh;
        if (kv0 >= kvlen)      a0[r] = -1e30f;
        if (kv0 + 32 >= kvlen) a1[r] = -1e30f;
      }
    }
  };

  auto finishTile = [&](f32x16& s0f, f32x16& s1f) {
    float mx[16];
#pragma unroll
    for (int r = 0; r < 16; ++r) mx[r] = fmaxf(s0f[r], s1f[r]);
#pragma unroll
    for (int w = 8; w; w >>= 1)
#pragma unroll
      for (int r = 0; r < w; ++r) mx[r] = fmaxf(mx[r], mx[r + w]);
    float pm = fmaxf(mx[0], __shfl_xor(mx[0], 32, 64));
    const bool defer = __all(pm <= m_run + 8.f);   // T13 (log2 domain)
    const float mn = defer ? m_run : fmaxf(m_run, pm);
#pragma unroll
    for (int r = 0; r < 16; ++r) {
      s0f[r] = __builtin_amdgcn_exp2f(s0f[r] - mn);
      s1f[r] = __builtin_amdgcn_exp2f(s1f[r] - mn);
    }
    float sm[16];
#pragma unroll
    for (int r = 0; r < 16; ++r) sm[r] = s0f[r] + s1f[r];
#pragma unroll
    for (int w = 8; w; w >>= 1)
#pragma unroll
      for (int r = 0; r < w; ++r) sm[r] += sm[r + w];
    float sum = sm[0] + __shfl_xor(sm[0], 32, 64);
    if (defer) {
      l_run += sum;
    } else {
      float al = __builtin_amdgcn_exp2f(m_run - mn);
      l_run = l_run * al + sum;
      m_run = mn;
#pragma unroll
      for (int i = 0; i < 4; ++i)
#pragma unroll
        for (int j = 0; j < 16; ++j) Oc[i][j] *= al;
    }
#pragma unroll
    for (int m = 0; m < 8; ++m) {
      w0[m] = pk2(s0f[2 * m], s0f[2 * m + 1]);
      w1[m] = pk2(s1f[2 * m], s1f[2 * m + 1]);
    }
  };

  auto doPV = [&](int cur) {
    __builtin_amdgcn_s_setprio(1);
#pragma unroll
    for (int s = 0; s < 4; ++s) {
      const unsigned int* w = (s < 2) ? w0 : w1;
      const int lo4 = (s & 1) * 4;
      unsigned int x0 = __shfl_xor(w[lo4 + 2], 32, 64);
      unsigned int x1 = __shfl_xor(w[lo4 + 3], 32, 64);
      unsigned int y0 = __shfl_xor(w[lo4],     32, 64);
      unsigned int y1 = __shfl_xor(w[lo4 + 1], 32, 64);
      unsigned int fw[4];
      fw[0] = hh ? x0 : w[lo4];
      fw[1] = hh ? x1 : w[lo4 + 1];
      fw[2] = hh ? w[lo4 + 2] : y0;
      fw[3] = hh ? w[lo4 + 3] : y1;
      short8 pb = *(const short8*)fw;
#pragma unroll
      for (int dt = 0; dt < 4; ++dt) {
        int d = dt * 32 + l31;
        int byte = (d * 128 + s * 32 + hh * 16) ^ ((d & 7) << 4);
        short8 vf = *(const short8*)((const char*)&Vt[cur][0] + byte);
        Oc[dt] = MFMA32(vf, pb, Oc[dt]);
      }
    }
    __builtin_amdgcn_s_setprio(0);
  };

  const int nt = (kvlen + 63) >> 6;

  // prologue: stage tile 0
  issueK(qkv, h, 0, kvlen, woff, tid, &Kl[0][0]);
  issueV(vt, h, 0, kvlen, woff, tid, &Vt[0][0]);
  __syncthreads();

  for (int t = 0; t < nt; ++t) {
    const int cur = t & 1;
    if (t + 1 < nt) {
      issueK(qkv, h, t + 1, kvlen, woff, tid, &Kl[cur ^ 1][0]);
      issueV(vt, h, t + 1, kvlen, woff, tid, &Vt[cur ^ 1][0]);
    }
    f32x16 s0, s1;
    computeQK(t, cur, s0, s1);
    finishTile(s0, s1);
    doPV(cur);
    __syncthreads();   // drains prefetch gl16 (vmcnt0); flips buffers
  }

  // --- epilogue ---
  const int qg = q0 + wave * 32 + l31;
  if (qg < chunk_end) {
    const float inv = 1.f / l_run;
    unsigned short* op = ob + (long)qg * 1536 + h * 128;
#pragma unroll
    for (int dt = 0; dt < 4; ++dt) {
#pragma unroll
      for (int gblk = 0; gblk < 4; ++gblk) {
        int d = dt * 32 + gblk * 8 + hh * 4;
        unsigned int u0 = pk2(Oc[dt][4 * gblk]     * inv, Oc[dt][4 * gblk + 1] * inv);
        unsigned int u1 = pk2(Oc[dt][4 * gblk + 2] * inv, Oc[dt][4 * gblk + 3] * inv);
        u32x2 uu; uu[0] = u0; uu[1] = u1;
        *(u32x2*)(op + d) = uu;
      }
    }
  }
}

// ---------------- launch ----------------
extern "C" void kernel_launch(void* const* d_in, const int* in_sizes, int n_in,
                              void* d_out, int out_size, void* d_ws, size_t ws_size,
                              hipStream_t stream)
{
  const float* x  = (const float*)d_in[0];
  const float* Wq = (const float*)d_in[1];
  const float* bq = (const float*)d_in[2];
  const float* Wk = (const float*)d_in[3];
  const float* bk = (const float*)d_in[4];
  const float* Wv = (const float*)d_in[5];
  const float* bv = (const float*)d_in[6];
  const float* Wo = (const float*)d_in[7];
  const float* bo = (const float*)d_in[8];
  const float* gq = (const float*)d_in[9];
  const float* gk = (const float*)d_in[10];
  const float* fc = (const float*)d_in[11];
  const float* fs = (const float*)d_in[12];

  char* ws = (char*)d_ws;
  unsigned short* xb   = (unsigned short*)(ws);               // dead after gemm0 -> reused as vt
  unsigned short* wcat = (unsigned short*)(ws + 21626880);
  unsigned short* wob  = (unsigned short*)(ws + 35782656);
  float*          bcat = (float*)(ws + 40501248);
  unsigned short* qkv  = (unsigned short*)(ws + 40519680);
  unsigned short* obuf = (unsigned short*)(ws + 105400320);
  unsigned short* vtb  = xb;                                  // V^T [1536][7040] bf16

  cvt_f32_bf16<<<2048, 256, 0, stream>>>(x,  xb,   10813440 / 4);
  cvt_f32_bf16<<<1024, 256, 0, stream>>>(Wq, wcat,            2359296 / 4);
  cvt_f32_bf16<<<1024, 256, 0, stream>>>(Wk, wcat + 2359296,  2359296 / 4);
  cvt_f32_bf16<<<1024, 256, 0, stream>>>(Wv, wcat + 4718592,  2359296 / 4);
  cvt_f32_bf16<<<1024, 256, 0, stream>>>(Wo, wob,             2359296 / 4);
  hipMemcpyAsync(bcat,        bq, 1536 * 4, hipMemcpyDeviceToDevice, stream);
  hipMemcpyAsync(bcat + 1536, bk, 1536 * 4, hipMemcpyDeviceToDevice, stream);
  hipMemcpyAsync(bcat + 3072, bv, 1536 * 4, hipMemcpyDeviceToDevice, stream);

  gemm_bt<0><<<dim3(36, 55), 256, 0, stream>>>(xb, wcat, bcat, qkv, nullptr, 1536, 4608);

  vtrans<<<dim3(110, 24), 256, 0, stream>>>(qkv, vtb);

  const float qsc = (float)(1.4426950408889634 / sqrt(128.0));
  normrope<<<7040, 256, 0, stream>>>(qkv, gq, fc, fs, 0,    qsc);
  normrope<<<7040, 256, 0, stream>>>(qkv, gk, fc, fs, 1536, 1.0f);

  attn_kern<<<dim3(7, 4, 12), 512, 0, stream>>>(qkv, vtb, obuf);

  gemm_bt<1><<<dim3(12, 55), 256, 0, stream>>>(obuf, wob, bo, nullptr, (float*)d_out, 1536, 1536);
}

// Round 10
// 439.065 us; speedup vs baseline: 1.8552x; 1.6998x over previous
//
#include <hip/hip_runtime.h>
#include <math.h>

typedef __attribute__((ext_vector_type(8))) short short8;
typedef __attribute__((ext_vector_type(4))) float f32x4;
typedef __attribute__((ext_vector_type(16))) float f32x16;
typedef __attribute__((ext_vector_type(4))) float f4;
typedef __attribute__((ext_vector_type(4))) unsigned short us4;
typedef __attribute__((ext_vector_type(2))) unsigned int u32x2;

#define MFMA16(a,b,c) __builtin_amdgcn_mfma_f32_16x16x32_bf16(a,b,c,0,0,0)
#define MFMA32(a,b,c) __builtin_amdgcn_mfma_f32_32x32x16_bf16(a,b,c,0,0,0)

__device__ __forceinline__ unsigned short f2bf(float f) {
  unsigned int u = __float_as_uint(f);
  u = (u + 0x7FFFu + ((u >> 16) & 1u)) >> 16;   // RNE
  return (unsigned short)u;
}
__device__ __forceinline__ float bf2f(unsigned short b) {
  return __uint_as_float(((unsigned int)b) << 16);
}
// pack two f32 -> two bf16 in one u32 (round-half-up + v_perm byte select)
__device__ __forceinline__ unsigned int pk2(float a, float b) {
  unsigned int au = __float_as_uint(a) + 0x8000u;
  unsigned int bu = __float_as_uint(b) + 0x8000u;
  return __builtin_amdgcn_perm(bu, au, 0x07060302u);  // {b.hi16, a.hi16}
}

typedef const __attribute__((address_space(1))) unsigned int* gas_t;
typedef __attribute__((address_space(3))) unsigned int* las_t;
__device__ __forceinline__ void gl16(const void* g, void* l) {
  __builtin_amdgcn_global_load_lds((gas_t)g, (las_t)l, 16, 0, 0);
}

// ---------------- f32 -> bf16 convert (x) ----------------
__global__ void cvt_f32_bf16(const float* __restrict__ in,
                             unsigned short* __restrict__ out, int n4) {
  int i = blockIdx.x * blockDim.x + threadIdx.x;
  const int stride = gridDim.x * blockDim.x;
  for (; i < n4; i += stride) {
    f4 v = ((const f4*)in)[i];
    us4 o;
    o[0] = f2bf(v[0]); o[1] = f2bf(v[1]); o[2] = f2bf(v[2]); o[3] = f2bf(v[3]);
    ((us4*)out)[i] = o;
  }
}

// ---------------- merged weight converts: blockIdx.y picks matrix ----------------
__global__ void cvt4_f32_bf16(const float* __restrict__ w0, const float* __restrict__ w1,
                              const float* __restrict__ w2, const float* __restrict__ w3,
                              unsigned short* __restrict__ o0, unsigned short* __restrict__ o1,
                              unsigned short* __restrict__ o2, unsigned short* __restrict__ o3,
                              int n4) {
  const float* in = (blockIdx.y == 0) ? w0 : (blockIdx.y == 1) ? w1 : (blockIdx.y == 2) ? w2 : w3;
  unsigned short* out = (blockIdx.y == 0) ? o0 : (blockIdx.y == 1) ? o1 : (blockIdx.y == 2) ? o2 : o3;
  int i = blockIdx.x * blockDim.x + threadIdx.x;
  const int stride = gridDim.x * blockDim.x;
  for (; i < n4; i += stride) {
    f4 v = ((const f4*)in)[i];
    us4 o;
    o[0] = f2bf(v[0]); o[1] = f2bf(v[1]); o[2] = f2bf(v[2]); o[3] = f2bf(v[3]);
    ((us4*)out)[i] = o;
  }
}

// ---------------- NT GEMM: out[m][n] = sum_k A[m][k]*B[n][k] + bias[n] ----------------
// 1-D grid with bijective XCD swizzle (T1): consecutive wg within an XCD walk
// n-tiles of one m-row -> A-panel reuse in that XCD's L2.
template<int F32OUT>
__global__ __launch_bounds__(256)
void gemm_bt(const unsigned short* __restrict__ A,
             const unsigned short* __restrict__ B,
             const float* __restrict__ bias,
             unsigned short* __restrict__ obf,
             float* __restrict__ of32,
             int K, int ldo, int nbx, int q, int r)
{
  // bijective XCD swizzle (m204): nwg = gridDim.x, q = nwg/8, r = nwg%8
  const int lin = blockIdx.x;
  const int xcd = lin & 7, local = lin >> 3;
  const int wg = (xcd < r) ? (xcd * (q + 1) + local) : (r * (q + 1) + (xcd - r) * q + local);
  const int m0 = (wg / nbx) * 128, n0 = (wg % nbx) * 128;

  const int tid = threadIdx.x;
  const int wave = tid >> 6, lane = tid & 63, lg = lane >> 4, lr = lane & 15;
  const int wr = wave >> 1, wc = wave & 1;

  __shared__ __align__(16) unsigned short Al[128 * 32];
  __shared__ __align__(16) unsigned short Bl[128 * 32];

  f32x4 acc[4][4];
#pragma unroll
  for (int m = 0; m < 4; ++m)
#pragma unroll
    for (int n = 0; n < 4; ++n) acc[m][n] = (f32x4){0.f, 0.f, 0.f, 0.f};

  const int r0 = tid >> 2, r1 = (tid + 256) >> 2;
  const int c0 = (tid & 3) * 8;
  const long arow0 = (long)(m0 + r0) * K, arow1 = (long)(m0 + r1) * K;
  const long brow0 = (long)(n0 + r0) * K, brow1 = (long)(n0 + r1) * K;

  for (int k0 = 0; k0 < K; k0 += 32) {
    gl16(A + arow0 + k0 + c0, (char*)Al + tid * 16);
    gl16(A + arow1 + k0 + c0, (char*)Al + (tid + 256) * 16);
    gl16(B + brow0 + k0 + c0, (char*)Bl + tid * 16);
    gl16(B + brow1 + k0 + c0, (char*)Bl + (tid + 256) * 16);
    __syncthreads();
    short8 af[4], bf[4];
#pragma unroll
    for (int m = 0; m < 4; ++m)
      af[m] = *(const short8*)(Al + (wr * 64 + m * 16 + lr) * 32 + lg * 8);
#pragma unroll
    for (int n = 0; n < 4; ++n)
      bf[n] = *(const short8*)(Bl + (wc * 64 + n * 16 + lr) * 32 + lg * 8);
#pragma unroll
    for (int m = 0; m < 4; ++m)
#pragma unroll
      for (int n = 0; n < 4; ++n)
        acc[m][n] = MFMA16(af[m], bf[n], acc[m][n]);
    __syncthreads();
  }

#pragma unroll
  for (int n = 0; n < 4; ++n) {
    const int col = n0 + wc * 64 + n * 16 + lr;
    const float bs = bias[col];
#pragma unroll
    for (int m = 0; m < 4; ++m) {
      const int row = m0 + wr * 64 + m * 16 + lg * 4;
#pragma unroll
      for (int r2 = 0; r2 < 4; ++r2) {
        float v = acc[m][n][r2] + bs;
        if (F32OUT) of32[(long)(row + r2) * ldo + col] = v;
        else        obf[(long)(row + r2) * ldo + col] = f2bf(v);
      }
    }
  }
}

// ---------------- fused RMSNorm + RoPE; blockIdx.y: 0 = Q, 1 = K ----------------
__global__ __launch_bounds__(256)
void normrope(unsigned short* __restrict__ qkv, const float* __restrict__ gq,
              const float* __restrict__ gk,
              const float* __restrict__ fc, const float* __restrict__ fs,
              float qsc)
{
  const int l = blockIdx.x, tid = threadIdx.x;
  const int colOff = blockIdx.y ? 1536 : 0;
  const float* g = blockIdx.y ? gk : gq;
  const float oscale = blockIdx.y ? 1.0f : qsc;
  __shared__ float rowbuf[1536];
  __shared__ float sred[4];
  unsigned short* rp = qkv + (long)l * 4608 + colOff;

  float ss = 0.f;
  if (tid < 192) {
    short8 v = *(const short8*)(rp + tid * 8);
#pragma unroll
    for (int e = 0; e < 8; ++e) {
      float f = bf2f((unsigned short)v[e]);
      rowbuf[tid * 8 + e] = f;
      ss += f * f;
    }
  }
#pragma unroll
  for (int m = 32; m; m >>= 1) ss += __shfl_xor(ss, m, 64);
  if ((tid & 63) == 0) sred[tid >> 6] = ss;
  __syncthreads();
  const float rs = rsqrtf((sred[0] + sred[1] + sred[2] + sred[3]) * (1.f / 1536.f) + 1e-6f);

  const int f_ = l / 880, rem = l % 880, h_ = rem / 40, w_ = rem % 40;
#pragma unroll
  for (int j = 0; j < 3; ++j) {
    int p = tid + j * 256;
    int head = p >> 6, c = p & 63;
    int e = head * 128 + 2 * c;
    int tr = (c < 22) ? f_ : ((c < 43) ? h_ : w_);
    float co = fc[tr * 64 + c], si = fs[tr * 64 + c];
    float xr = rowbuf[e] * rs * g[e];
    float xi = rowbuf[e + 1] * rs * g[e + 1];
    float yr = (xr * co - xi * si) * oscale;
    float yi = (xr * si + xi * co) * oscale;
    unsigned int pk = (unsigned int)f2bf(yr) | ((unsigned int)f2bf(yi) << 16);
    *(unsigned int*)(rp + e) = pk;
  }
}

// ---------------- attention staging helpers (256 threads) ----------------
__device__ __forceinline__ void issueK(const unsigned short* __restrict__ qkv,
                                       int h, int t, int kvlen, int woff, int tid,
                                       unsigned short* Kbuf)
{
#pragma unroll
  for (int i = 0; i < 4; ++i) {
    int s = i * 256 + tid;
    int kvl = s >> 4;
    int dc = (s & 15) ^ (kvl & 7);
    int j = t * 64 + kvl; j = j < kvlen ? j : kvlen - 1;
    int gk = j + (j >= 880 ? woff : 0);
    gl16(qkv + (long)gk * 4608 + 1536 + h * 128 + dc * 8, (char*)Kbuf + s * 16);
  }
}

__device__ __forceinline__ void loadV(const unsigned short* __restrict__ qkv,
                                      int h, int t, int kvlen, int woff, int tid,
                                      short8 vp[2][2])
{
#pragma unroll
  for (int i = 0; i < 2; ++i) {
    int task = i * 256 + tid;
    int dc = task & 15, kp = task >> 4;
    int kvl = kp * 2;
    int j0 = t * 64 + kvl, j1 = j0 + 1;
    j0 = j0 < kvlen ? j0 : kvlen - 1;
    j1 = j1 < kvlen ? j1 : kvlen - 1;
    int g0 = j0 + (j0 >= 880 ? woff : 0);
    int g1 = j1 + (j1 >= 880 ? woff : 0);
    vp[i][0] = *(const short8*)(qkv + (long)g0 * 4608 + 3072 + h * 128 + dc * 8);
    vp[i][1] = *(const short8*)(qkv + (long)g1 * 4608 + 3072 + h * 128 + dc * 8);
  }
}

__device__ __forceinline__ void writeV(int tid, short8 vp[2][2], unsigned short* Vt)
{
#pragma unroll
  for (int i = 0; i < 2; ++i) {
    int task = i * 256 + tid;
    int dc = task & 15, kp = task >> 4;
    int kvl = kp * 2;
#pragma unroll
    for (int e = 0; e < 8; ++e) {
      int d = dc * 8 + e;
      int byte = d * 128 + kvl * 2;
      byte ^= (((d & 7) ^ ((d >> 3) & 7)) << 4);
      *(unsigned int*)((char*)Vt + byte) =
          (unsigned int)(unsigned short)vp[i][0][e] |
          ((unsigned int)(unsigned short)vp[i][1][e] << 16);
    }
  }
}

// ---------------- chunked sink+window attention, 32x32 swapped-operand ----------------
// grid (14 qtiles, 4 chunks, 12 heads); 4 waves x 32 q-rows; KV tile 64.
// Cross-tile S-pipeline (T15): iter t = QK(t+1) || softmax(t) || PV(t).
// (R5-verified config: attn 227us, FETCH 188MB — do not change dispatch shape.)
__global__ __launch_bounds__(256, 2)
void attn_kern(const unsigned short* __restrict__ qkv,
               unsigned short* __restrict__ ob)
{
  const int qt = blockIdx.x, ci = blockIdx.y, h = blockIdx.z;
  const int tid = threadIdx.x, wave = tid >> 6, lane = tid & 63;
  const int l31 = lane & 31, hh = lane >> 5;
  const int chunk_start = ci * 1760, chunk_end = chunk_start + 1760;
  const int wstart = (ci == 0) ? 880 : ci * 1760;
  const int woff = wstart - 880;
  const int kvlen = 880 + (chunk_end - wstart);     // 1760 or 2640
  const int q0 = chunk_start + qt * 128;

  __shared__ __align__(16) unsigned short Kl[2][64 * 128];
  __shared__ __align__(16) unsigned short Vt[2][128 * 64];

  int qr = q0 + wave * 32 + l31;
  if (qr >= chunk_end) qr = chunk_end - 1;
  const unsigned short* qp = qkv + (long)qr * 4608 + h * 128;
  short8 qf[8];
#pragma unroll
  for (int st = 0; st < 8; ++st) qf[st] = *(const short8*)(qp + st * 16 + hh * 8);

  f32x16 Oc[4];
#pragma unroll
  for (int i = 0; i < 4; ++i)
#pragma unroll
    for (int j = 0; j < 16; ++j) Oc[i][j] = 0.f;
  float m_run = -1e30f, l_run = 0.f;
  unsigned int w0[8], w1[8];

  auto computeQK = [&](int t, int cur, f32x16* S0, f32x16* S1) {
    f32x16 a0, a1;
#pragma unroll
    for (int j = 0; j < 16; ++j) { a0[j] = 0.f; a1[j] = 0.f; }
    __builtin_amdgcn_s_setprio(1);
#pragma unroll
    for (int st = 0; st < 8; ++st) {
      int off = 32 * st + 16 * hh;
      int b0 = l31 * 256 + (off ^ ((l31 & 7) << 4));
      short8 k0 = *(const short8*)((const char*)&Kl[cur][0] + b0);
      a0 = MFMA32(k0, qf[st], a0);
      int b1 = (32 + l31) * 256 + (off ^ ((l31 & 7) << 4));
      short8 k1 = *(const short8*)((const char*)&Kl[cur][0] + b1);
      a1 = MFMA32(k1, qf[st], a1);
    }
    __builtin_amdgcn_s_setprio(0);
    if (t * 64 + 64 > kvlen) {       // uniform: tail tile only
#pragma unroll
      for (int r = 0; r < 16; ++r) {
        int kv0 = t * 64 + (r & 3) + 8 * (r >> 2) + 4 * hh;
        if (kv0 >= kvlen)      a0[r] = -1e30f;
        if (kv0 + 32 >= kvlen) a1[r] = -1e30f;
      }
    }
    *S0 = a0; *S1 = a1;
  };

  auto finishTile = [&](f32x16& s0f, f32x16& s1f) {
    float mx[16];
#pragma unroll
    for (int r = 0; r < 16; ++r) mx[r] = fmaxf(s0f[r], s1f[r]);
#pragma unroll
    for (int w = 8; w; w >>= 1)
#pragma unroll
      for (int r = 0; r < w; ++r) mx[r] = fmaxf(mx[r], mx[r + w]);
    float pm = fmaxf(mx[0], __shfl_xor(mx[0], 32, 64));
    const bool defer = __all(pm <= m_run + 8.f);   // T13 (log2 domain)
    const float mn = defer ? m_run : fmaxf(m_run, pm);
#pragma unroll
    for (int r = 0; r < 16; ++r) {
      s0f[r] = __builtin_amdgcn_exp2f(s0f[r] - mn);
      s1f[r] = __builtin_amdgcn_exp2f(s1f[r] - mn);
    }
    float sm[16];
#pragma unroll
    for (int r = 0; r < 16; ++r) sm[r] = s0f[r] + s1f[r];
#pragma unroll
    for (int w = 8; w; w >>= 1)
#pragma unroll
      for (int r = 0; r < w; ++r) sm[r] += sm[r + w];
    float sum = sm[0] + __shfl_xor(sm[0], 32, 64);
    if (defer) {
      l_run += sum;
    } else {
      float al = __builtin_amdgcn_exp2f(m_run - mn);
      l_run = l_run * al + sum;
      m_run = mn;
#pragma unroll
      for (int i = 0; i < 4; ++i)
#pragma unroll
        for (int j = 0; j < 16; ++j) Oc[i][j] *= al;
    }
#pragma unroll
    for (int m = 0; m < 8; ++m) {
      w0[m] = pk2(s0f[2 * m], s0f[2 * m + 1]);
      w1[m] = pk2(s1f[2 * m], s1f[2 * m + 1]);
    }
  };

  auto doPV = [&](int cur) {
    __builtin_amdgcn_s_setprio(1);
#pragma unroll
    for (int s = 0; s < 4; ++s) {
      const unsigned int* w = (s < 2) ? w0 : w1;
      const int lo4 = (s & 1) * 4;
      unsigned int x0 = __shfl_xor(w[lo4 + 2], 32, 64);
      unsigned int x1 = __shfl_xor(w[lo4 + 3], 32, 64);
      unsigned int y0 = __shfl_xor(w[lo4],     32, 64);
      unsigned int y1 = __shfl_xor(w[lo4 + 1], 32, 64);
      unsigned int fw[4];
      fw[0] = hh ? x0 : w[lo4];
      fw[1] = hh ? x1 : w[lo4 + 1];
      fw[2] = hh ? w[lo4 + 2] : y0;
      fw[3] = hh ? w[lo4 + 3] : y1;
      short8 pb = *(const short8*)fw;
#pragma unroll
      for (int dt = 0; dt < 4; ++dt) {
        int d = dt * 32 + l31;
        int byte = d * 128 + s * 32 + hh * 16;
        byte ^= (((d & 7) ^ ((d >> 3) & 7)) << 4);
        short8 vf = *(const short8*)((const char*)&Vt[cur][0] + byte);
        Oc[dt] = MFMA32(vf, pb, Oc[dt]);
      }
    }
    __builtin_amdgcn_s_setprio(0);
  };

  const int nt = (kvlen + 63) >> 6;
  short8 vp[2][2];

  // prologue: stage K0,K1,V0; compute QK(0)
  issueK(qkv, h, 0, kvlen, woff, tid, &Kl[0][0]);
  if (nt > 1) issueK(qkv, h, 1, kvlen, woff, tid, &Kl[1][0]);
  loadV(qkv, h, 0, kvlen, woff, tid, vp);
  writeV(tid, vp, &Vt[0][0]);
  __syncthreads();

  f32x16 sp0, sp1;
  computeQK(0, 0, &sp0, &sp1);
  __syncthreads();    // all waves done reading Kl[0] before iter-0 prefetch overwrites it

  for (int t = 0; t < nt - 1; ++t) {
    const int cur = t & 1;
    if (t + 2 < nt) issueK(qkv, h, t + 2, kvlen, woff, tid, &Kl[cur][0]);
    loadV(qkv, h, t + 1, kvlen, woff, tid, vp);

    f32x16 sc0, sc1;
    computeQK(t + 1, cur ^ 1, &sc0, &sc1);   // MFMA pipe busy...
    finishTile(sp0, sp1);                    // ...while VALU runs softmax(t)
    writeV(tid, vp, &Vt[cur ^ 1][0]);
    doPV(cur);                               // PV(t)
    __syncthreads();                         // drains gl16 + V writes; flips buffers
    sp0 = sc0; sp1 = sc1;
  }
  finishTile(sp0, sp1);
  doPV((nt - 1) & 1);

  // --- epilogue ---
  const int qg = q0 + wave * 32 + l31;
  if (qg < chunk_end) {
    const float inv = 1.f / l_run;
    unsigned short* op = ob + (long)qg * 1536 + h * 128;
#pragma unroll
    for (int dt = 0; dt < 4; ++dt) {
#pragma unroll
      for (int gblk = 0; gblk < 4; ++gblk) {
        int d = dt * 32 + gblk * 8 + hh * 4;
        unsigned int u0 = pk2(Oc[dt][4 * gblk]     * inv, Oc[dt][4 * gblk + 1] * inv);
        unsigned int u1 = pk2(Oc[dt][4 * gblk + 2] * inv, Oc[dt][4 * gblk + 3] * inv);
        u32x2 uu; uu[0] = u0; uu[1] = u1;
        *(u32x2*)(op + d) = uu;
      }
    }
  }
}

// ---------------- launch ----------------
extern "C" void kernel_launch(void* const* d_in, const int* in_sizes, int n_in,
                              void* d_out, int out_size, void* d_ws, size_t ws_size,
                              hipStream_t stream)
{
  const float* x  = (const float*)d_in[0];
  const float* Wq = (const float*)d_in[1];
  const float* bq = (const float*)d_in[2];
  const float* Wk = (const float*)d_in[3];
  const float* bk = (const float*)d_in[4];
  const float* Wv = (const float*)d_in[5];
  const float* bv = (const float*)d_in[6];
  const float* Wo = (const float*)d_in[7];
  const float* bo = (const float*)d_in[8];
  const float* gq = (const float*)d_in[9];
  const float* gk = (const float*)d_in[10];
  const float* fc = (const float*)d_in[11];
  const float* fs = (const float*)d_in[12];

  char* ws = (char*)d_ws;
  unsigned short* xb   = (unsigned short*)(ws);
  unsigned short* wcat = (unsigned short*)(ws + 21626880);
  unsigned short* wob  = (unsigned short*)(ws + 35782656);
  float*          bcat = (float*)(ws + 40501248);
  unsigned short* qkv  = (unsigned short*)(ws + 40519680);
  unsigned short* obuf = (unsigned short*)(ws + 105400320);

  cvt_f32_bf16<<<2048, 256, 0, stream>>>(x, xb, 10813440 / 4);
  cvt4_f32_bf16<<<dim3(576, 4), 256, 0, stream>>>(
      Wq, Wk, Wv, Wo,
      wcat, wcat + 2359296, wcat + 4718592, wob, 2359296 / 4);
  hipMemcpyAsync(bcat,        bq, 1536 * 4, hipMemcpyDeviceToDevice, stream);
  hipMemcpyAsync(bcat + 1536, bk, 1536 * 4, hipMemcpyDeviceToDevice, stream);
  hipMemcpyAsync(bcat + 3072, bv, 1536 * 4, hipMemcpyDeviceToDevice, stream);

  // QKV projection: [7040x4608] = xb . wcat^T + bcat ; nwg=1980, q=247, r=4
  gemm_bt<0><<<1980, 256, 0, stream>>>(xb, wcat, bcat, qkv, nullptr, 1536, 4608,
                                       36, 1980 / 8, 1980 % 8);

  const float qsc = (float)(1.4426950408889634 / sqrt(128.0));
  normrope<<<dim3(7040, 2), 256, 0, stream>>>(qkv, gq, gk, fc, fs, qsc);

  attn_kern<<<dim3(14, 4, 12), 256, 0, stream>>>(qkv, obuf);

  // output projection: d_out = obuf . Wo^T + bo (f32) ; nwg=660, q=82, r=4
  gemm_bt<1><<<660, 256, 0, stream>>>(obuf, wob, bo, nullptr, (float*)d_out, 1536, 1536,
                                      12, 660 / 8, 660 % 8);
}

// Round 11
// 434.015 us; speedup vs baseline: 1.8768x; 1.0116x over previous
//
#include <hip/hip_runtime.h>
#include <math.h>

typedef __attribute__((ext_vector_type(8))) short short8;
typedef __attribute__((ext_vector_type(4))) float f32x4;
typedef __attribute__((ext_vector_type(16))) float f32x16;
typedef __attribute__((ext_vector_type(4))) float f4;
typedef __attribute__((ext_vector_type(4))) unsigned short us4;
typedef __attribute__((ext_vector_type(2))) unsigned int u32x2;

#define MFMA16(a,b,c) __builtin_amdgcn_mfma_f32_16x16x32_bf16(a,b,c,0,0,0)
#define MFMA32(a,b,c) __builtin_amdgcn_mfma_f32_32x32x16_bf16(a,b,c,0,0,0)

__device__ __forceinline__ unsigned short f2bf(float f) {
  unsigned int u = __float_as_uint(f);
  u = (u + 0x7FFFu + ((u >> 16) & 1u)) >> 16;   // RNE
  return (unsigned short)u;
}
__device__ __forceinline__ float bf2f(unsigned short b) {
  return __uint_as_float(((unsigned int)b) << 16);
}
__device__ __forceinline__ unsigned int pk2(float a, float b) {
  unsigned int au = __float_as_uint(a) + 0x8000u;
  unsigned int bu = __float_as_uint(b) + 0x8000u;
  return __builtin_amdgcn_perm(bu, au, 0x07060302u);
}

typedef const __attribute__((address_space(1))) unsigned int* gas_t;
typedef __attribute__((address_space(3))) unsigned int* las_t;
__device__ __forceinline__ void gl16(const void* g, void* l) {
  __builtin_amdgcn_global_load_lds((gas_t)g, (las_t)l, 16, 0, 0);
}

// ---------------- f32 -> bf16 convert (x) ----------------
__global__ void cvt_f32_bf16(const float* __restrict__ in,
                             unsigned short* __restrict__ out, int n4) {
  int i = blockIdx.x * blockDim.x + threadIdx.x;
  const int stride = gridDim.x * blockDim.x;
  for (; i < n4; i += stride) {
    f4 v = ((const f4*)in)[i];
    us4 o;
    o[0] = f2bf(v[0]); o[1] = f2bf(v[1]); o[2] = f2bf(v[2]); o[3] = f2bf(v[3]);
    ((us4*)out)[i] = o;
  }
}

// ---------------- merged weight converts ----------------
__global__ void cvt4_f32_bf16(const float* __restrict__ w0, const float* __restrict__ w1,
                              const float* __restrict__ w2, const float* __restrict__ w3,
                              unsigned short* __restrict__ o0, unsigned short* __restrict__ o1,
                              unsigned short* __restrict__ o2, unsigned short* __restrict__ o3,
                              int n4) {
  const float* in = (blockIdx.y == 0) ? w0 : (blockIdx.y == 1) ? w1 : (blockIdx.y == 2) ? w2 : w3;
  unsigned short* out = (blockIdx.y == 0) ? o0 : (blockIdx.y == 1) ? o1 : (blockIdx.y == 2) ? o2 : o3;
  int i = blockIdx.x * blockDim.x + threadIdx.x;
  const int stride = gridDim.x * blockDim.x;
  for (; i < n4; i += stride) {
    f4 v = ((const f4*)in)[i];
    us4 o;
    o[0] = f2bf(v[0]); o[1] = f2bf(v[1]); o[2] = f2bf(v[2]); o[3] = f2bf(v[3]);
    ((us4*)out)[i] = o;
  }
}

// ---------------- 8-phase 256^2 NT GEMM (gemm0: qkv = xb . wcat^T + bcat) ----------------
// M=7168 (7040 padded), N=4608, K=1536. 504 blocks (28x18), 512 thr = 8 waves (2M x 4N).
// BK=64; LDS 128KB: A,B x 2 halves x dbuf. T2 swizzle ^((row&7)<<4) both sides (rule 21).
// Per K-tile 4 phases; counted vmcnt(4) once per K-tile (T4); setprio around MFMA (T5).
__global__ __launch_bounds__(512, 1)
void gemm8(const unsigned short* __restrict__ A,
           const unsigned short* __restrict__ B,
           const float* __restrict__ bias,
           unsigned short* __restrict__ out)
{
  const int bi = blockIdx.x;
  const int wg = (bi & 7) * 63 + (bi >> 3);      // bijective XCD swizzle (504 = 8*63)
  const int m0 = (wg / 18) * 256, n0 = (wg % 18) * 256;

  const int tid = threadIdx.x;
  const int lane = tid & 63, lg = lane >> 4, lr = lane & 15;
  const int wave = tid >> 6, wr = wave >> 2, wc = wave & 3;

  __shared__ __align__(16) unsigned short Ab[2][256 * 64];
  __shared__ __align__(16) unsigned short Bb[2][256 * 64];

  f32x4 acc[8][4];
#pragma unroll
  for (int m = 0; m < 8; ++m)
#pragma unroll
    for (int n = 0; n < 4; ++n) acc[m][n] = (f32x4){0.f, 0.f, 0.f, 0.f};

  // stage one 128-row half-tile: 512 thr x 2 x 16B = 16KB; linear LDS dest,
  // inverse-swizzled source column (involution c ^ (row&7)).
  auto stage = [&](const unsigned short* P, int rowBase, int t, unsigned short* lbase) {
    const int k0 = t * 64;
#pragma unroll
    for (int i = 0; i < 2; ++i) {
      int s = i * 512 + tid;           // 0..1023
      int row = s >> 3, c = s & 7;
      int cc = c ^ (row & 7);
      gl16(P + (long)(rowBase + row) * 1536 + k0 + cc * 8, (char*)lbase + s * 16);
    }
  };
  auto rdA = [&](int buf, int mr, int k) -> short8 {
    int row = mr + lr;
    int byte = (row * 128 + (k + lg * 8) * 2) ^ ((row & 7) << 4);
    return *(const short8*)((const char*)&Ab[buf][0] + byte);
  };
  auto rdB = [&](int buf, int nr, int k) -> short8 {
    int row = nr + lr;
    int byte = (row * 128 + (k + lg * 8) * 2) ^ ((row & 7) << 4);
    return *(const short8*)((const char*)&Bb[buf][0] + byte);
  };

  // prologue: A(0) lo/hi, B(0) lo/hi, B(1) lo/hi  -> wait all but B(1)
  stage(A, m0,       0, &Ab[0][0]);
  stage(A, m0 + 128, 0, &Ab[0][128 * 64]);
  stage(B, n0,       0, &Bb[0][0]);
  stage(B, n0 + 128, 0, &Bb[0][128 * 64]);
  stage(B, n0,       1, &Bb[1][0]);
  stage(B, n0 + 128, 1, &Bb[1][128 * 64]);
  asm volatile("s_waitcnt vmcnt(4)" ::: "memory");
  __builtin_amdgcn_s_barrier();

  for (int T = 0; T < 24; ++T) {
    const int cur = T & 1;
    const int tA = (T + 1 < 24) ? T + 1 : 23;   // clamped global addr; parity from T+1
    const int tB = (T + 2 < 24) ? T + 2 : 23;   // parity (T+2)&1 == cur
    short8 bfr[4][2];
#pragma unroll
    for (int p = 0; p < 4; ++p) {
      // ---- stage one half-tile (region freed >=2 barriers ago) ----
      if (p == 0)      stage(A, m0,       tA, &Ab[cur ^ 1][0]);
      else if (p == 1) stage(A, m0 + 128, tA, &Ab[cur ^ 1][128 * 64]);
      else if (p == 2) stage(B, n0,       tB, &Bb[cur][0]);
      else             stage(B, n0 + 128, tB, &Bb[cur][128 * 64]);
      // ---- ds_read register subtile ----
      if (p == 0) {
#pragma unroll
        for (int n = 0; n < 4; ++n) {
          bfr[n][0] = rdB(cur, wc * 64 + n * 16, 0);
          bfr[n][1] = rdB(cur, wc * 64 + n * 16, 32);
        }
      }
      short8 afr[2][2];
#pragma unroll
      for (int m2 = 0; m2 < 2; ++m2) {
        afr[m2][0] = rdA(cur, wr * 128 + p * 32 + m2 * 16, 0);
        afr[m2][1] = rdA(cur, wr * 128 + p * 32 + m2 * 16, 32);
      }
      if (p == 3) asm volatile("s_waitcnt vmcnt(4)" ::: "memory");  // next tile landed
      __builtin_amdgcn_s_barrier();
      __builtin_amdgcn_s_setprio(1);
#pragma unroll
      for (int m2 = 0; m2 < 2; ++m2)
#pragma unroll
        for (int n = 0; n < 4; ++n) {
          acc[p * 2 + m2][n] = MFMA16(afr[m2][0], bfr[n][0], acc[p * 2 + m2][n]);
          acc[p * 2 + m2][n] = MFMA16(afr[m2][1], bfr[n][1], acc[p * 2 + m2][n]);
        }
      __builtin_amdgcn_s_setprio(0);
      __builtin_amdgcn_s_barrier();
    }
  }
  asm volatile("s_waitcnt vmcnt(0)" ::: "memory");  // drain dangling clamped stages

  // epilogue
#pragma unroll
  for (int n = 0; n < 4; ++n) {
    const int col = n0 + wc * 64 + n * 16 + lr;
    const float bs = bias[col];
#pragma unroll
    for (int m = 0; m < 8; ++m) {
      const int row = m0 + wr * 128 + m * 16 + lg * 4;
#pragma unroll
      for (int r = 0; r < 4; ++r) {
        if (row + r < 7040)
          out[(long)(row + r) * 4608 + col] = f2bf(acc[m][n][r] + bs);
      }
    }
  }
}

// ---------------- 128^2 NT GEMM (gemm1) ----------------
__global__ __launch_bounds__(256)
void gemm_bt(const unsigned short* __restrict__ A,
             const unsigned short* __restrict__ B,
             const float* __restrict__ bias,
             float* __restrict__ of32,
             int K, int ldo, int nbx, int q, int r)
{
  const int lin = blockIdx.x;
  const int xcd = lin & 7, local = lin >> 3;
  const int wg = (xcd < r) ? (xcd * (q + 1) + local) : (r * (q + 1) + (xcd - r) * q + local);
  const int m0 = (wg / nbx) * 128, n0 = (wg % nbx) * 128;

  const int tid = threadIdx.x;
  const int wave = tid >> 6, lane = tid & 63, lg = lane >> 4, lr = lane & 15;
  const int wr = wave >> 1, wc = wave & 1;

  __shared__ __align__(16) unsigned short Al[128 * 32];
  __shared__ __align__(16) unsigned short Bl[128 * 32];

  f32x4 acc[4][4];
#pragma unroll
  for (int m = 0; m < 4; ++m)
#pragma unroll
    for (int n = 0; n < 4; ++n) acc[m][n] = (f32x4){0.f, 0.f, 0.f, 0.f};

  const int r0 = tid >> 2, r1 = (tid + 256) >> 2;
  const int c0 = (tid & 3) * 8;
  const long arow0 = (long)(m0 + r0) * K, arow1 = (long)(m0 + r1) * K;
  const long brow0 = (long)(n0 + r0) * K, brow1 = (long)(n0 + r1) * K;

  for (int k0 = 0; k0 < K; k0 += 32) {
    gl16(A + arow0 + k0 + c0, (char*)Al + tid * 16);
    gl16(A + arow1 + k0 + c0, (char*)Al + (tid + 256) * 16);
    gl16(B + brow0 + k0 + c0, (char*)Bl + tid * 16);
    gl16(B + brow1 + k0 + c0, (char*)Bl + (tid + 256) * 16);
    __syncthreads();
    short8 af[4], bf[4];
#pragma unroll
    for (int m = 0; m < 4; ++m)
      af[m] = *(const short8*)(Al + (wr * 64 + m * 16 + lr) * 32 + lg * 8);
#pragma unroll
    for (int n = 0; n < 4; ++n)
      bf[n] = *(const short8*)(Bl + (wc * 64 + n * 16 + lr) * 32 + lg * 8);
#pragma unroll
    for (int m = 0; m < 4; ++m)
#pragma unroll
      for (int n = 0; n < 4; ++n)
        acc[m][n] = MFMA16(af[m], bf[n], acc[m][n]);
    __syncthreads();
  }

#pragma unroll
  for (int n = 0; n < 4; ++n) {
    const int col = n0 + wc * 64 + n * 16 + lr;
    const float bs = bias[col];
#pragma unroll
    for (int m = 0; m < 4; ++m) {
      const int row = m0 + wr * 64 + m * 16 + lg * 4;
#pragma unroll
      for (int r2 = 0; r2 < 4; ++r2)
        of32[(long)(row + r2) * ldo + col] = acc[m][n][r2] + bs;
    }
  }
}

// ---------------- fused RMSNorm + RoPE; blockIdx.y: 0 = Q, 1 = K ----------------
__global__ __launch_bounds__(256)
void normrope(unsigned short* __restrict__ qkv, const float* __restrict__ gq,
              const float* __restrict__ gk,
              const float* __restrict__ fc, const float* __restrict__ fs,
              float qsc)
{
  const int l = blockIdx.x, tid = threadIdx.x;
  const int colOff = blockIdx.y ? 1536 : 0;
  const float* g = blockIdx.y ? gk : gq;
  const float oscale = blockIdx.y ? 1.0f : qsc;
  __shared__ float rowbuf[1536];
  __shared__ float sred[4];
  unsigned short* rp = qkv + (long)l * 4608 + colOff;

  float ss = 0.f;
  if (tid < 192) {
    short8 v = *(const short8*)(rp + tid * 8);
#pragma unroll
    for (int e = 0; e < 8; ++e) {
      float f = bf2f((unsigned short)v[e]);
      rowbuf[tid * 8 + e] = f;
      ss += f * f;
    }
  }
#pragma unroll
  for (int m = 32; m; m >>= 1) ss += __shfl_xor(ss, m, 64);
  if ((tid & 63) == 0) sred[tid >> 6] = ss;
  __syncthreads();
  const float rs = rsqrtf((sred[0] + sred[1] + sred[2] + sred[3]) * (1.f / 1536.f) + 1e-6f);

  const int f_ = l / 880, rem = l % 880, h_ = rem / 40, w_ = rem % 40;
#pragma unroll
  for (int j = 0; j < 3; ++j) {
    int p = tid + j * 256;
    int head = p >> 6, c = p & 63;
    int e = head * 128 + 2 * c;
    int tr = (c < 22) ? f_ : ((c < 43) ? h_ : w_);
    float co = fc[tr * 64 + c], si = fs[tr * 64 + c];
    float xr = rowbuf[e] * rs * g[e];
    float xi = rowbuf[e + 1] * rs * g[e + 1];
    float yr = (xr * co - xi * si) * oscale;
    float yi = (xr * si + xi * co) * oscale;
    unsigned int pk = (unsigned int)f2bf(yr) | ((unsigned int)f2bf(yi) << 16);
    *(unsigned int*)(rp + e) = pk;
  }
}

// ---------------- attention staging helpers (256 threads) ----------------
__device__ __forceinline__ void issueK(const unsigned short* __restrict__ qkv,
                                       int h, int t, int kvlen, int woff, int tid,
                                       unsigned short* Kbuf)
{
#pragma unroll
  for (int i = 0; i < 4; ++i) {
    int s = i * 256 + tid;
    int kvl = s >> 4;
    int dc = (s & 15) ^ (kvl & 7);
    int j = t * 64 + kvl; j = j < kvlen ? j : kvlen - 1;
    int gk = j + (j >= 880 ? woff : 0);
    gl16(qkv + (long)gk * 4608 + 1536 + h * 128 + dc * 8, (char*)Kbuf + s * 16);
  }
}

__device__ __forceinline__ void loadV(const unsigned short* __restrict__ qkv,
                                      int h, int t, int kvlen, int woff, int tid,
                                      short8 vp[2][2])
{
#pragma unroll
  for (int i = 0; i < 2; ++i) {
    int task = i * 256 + tid;
    int dc = task & 15, kp = task >> 4;
    int kvl = kp * 2;
    int j0 = t * 64 + kvl, j1 = j0 + 1;
    j0 = j0 < kvlen ? j0 : kvlen - 1;
    j1 = j1 < kvlen ? j1 : kvlen - 1;
    int g0 = j0 + (j0 >= 880 ? woff : 0);
    int g1 = j1 + (j1 >= 880 ? woff : 0);
    vp[i][0] = *(const short8*)(qkv + (long)g0 * 4608 + 3072 + h * 128 + dc * 8);
    vp[i][1] = *(const short8*)(qkv + (long)g1 * 4608 + 3072 + h * 128 + dc * 8);
  }
}

__device__ __forceinline__ void writeV(int tid, short8 vp[2][2], unsigned short* Vt)
{
#pragma unroll
  for (int i = 0; i < 2; ++i) {
    int task = i * 256 + tid;
    int dc = task & 15, kp = task >> 4;
    int kvl = kp * 2;
#pragma unroll
    for (int e = 0; e < 8; ++e) {
      int d = dc * 8 + e;
      int byte = d * 128 + kvl * 2;
      byte ^= (((d & 7) ^ ((d >> 3) & 7)) << 4);
      *(unsigned int*)((char*)Vt + byte) =
          (unsigned int)(unsigned short)vp[i][0][e] |
          ((unsigned int)(unsigned short)vp[i][1][e] << 16);
    }
  }
}

// ---------------- chunked sink+window attention (R5/R9-verified config) ----------------
__global__ __launch_bounds__(256, 2)
void attn_kern(const unsigned short* __restrict__ qkv,
               unsigned short* __restrict__ ob)
{
  const int qt = blockIdx.x, ci = blockIdx.y, h = blockIdx.z;
  const int tid = threadIdx.x, wave = tid >> 6, lane = tid & 63;
  const int l31 = lane & 31, hh = lane >> 5;
  const int chunk_start = ci * 1760, chunk_end = chunk_start + 1760;
  const int wstart = (ci == 0) ? 880 : ci * 1760;
  const int woff = wstart - 880;
  const int kvlen = 880 + (chunk_end - wstart);
  const int q0 = chunk_start + qt * 128;

  __shared__ __align__(16) unsigned short Kl[2][64 * 128];
  __shared__ __align__(16) unsigned short Vt[2][128 * 64];

  int qr = q0 + wave * 32 + l31;
  if (qr >= chunk_end) qr = chunk_end - 1;
  const unsigned short* qp = qkv + (long)qr * 4608 + h * 128;
  short8 qf[8];
#pragma unroll
  for (int st = 0; st < 8; ++st) qf[st] = *(const short8*)(qp + st * 16 + hh * 8);

  f32x16 Oc[4];
#pragma unroll
  for (int i = 0; i < 4; ++i)
#pragma unroll
    for (int j = 0; j < 16; ++j) Oc[i][j] = 0.f;
  float m_run = -1e30f, l_run = 0.f;
  unsigned int w0[8], w1[8];

  auto computeQK = [&](int t, int cur, f32x16* S0, f32x16* S1) {
    f32x16 a0, a1;
#pragma unroll
    for (int j = 0; j < 16; ++j) { a0[j] = 0.f; a1[j] = 0.f; }
    __builtin_amdgcn_s_setprio(1);
#pragma unroll
    for (int st = 0; st < 8; ++st) {
      int off = 32 * st + 16 * hh;
      int b0 = l31 * 256 + (off ^ ((l31 & 7) << 4));
      short8 k0 = *(const short8*)((const char*)&Kl[cur][0] + b0);
      a0 = MFMA32(k0, qf[st], a0);
      int b1 = (32 + l31) * 256 + (off ^ ((l31 & 7) << 4));
      short8 k1 = *(const short8*)((const char*)&Kl[cur][0] + b1);
      a1 = MFMA32(k1, qf[st], a1);
    }
    __builtin_amdgcn_s_setprio(0);
    if (t * 64 + 64 > kvlen) {
#pragma unroll
      for (int r = 0; r < 16; ++r) {
        int kv0 = t * 64 + (r & 3) + 8 * (r >> 2) + 4 * hh;
        if (kv0 >= kvlen)      a0[r] = -1e30f;
        if (kv0 + 32 >= kvlen) a1[r] = -1e30f;
      }
    }
    *S0 = a0; *S1 = a1;
  };

  auto finishTile = [&](f32x16& s0f, f32x16& s1f) {
    float mx[16];
#pragma unroll
    for (int r = 0; r < 16; ++r) mx[r] = fmaxf(s0f[r], s1f[r]);
#pragma unroll
    for (int w = 8; w; w >>= 1)
#pragma unroll
      for (int r = 0; r < w; ++r) mx[r] = fmaxf(mx[r], mx[r + w]);
    float pm = fmaxf(mx[0], __shfl_xor(mx[0], 32, 64));
    const bool defer = __all(pm <= m_run + 8.f);
    const float mn = defer ? m_run : fmaxf(m_run, pm);
#pragma unroll
    for (int r = 0; r < 16; ++r) {
      s0f[r] = __builtin_amdgcn_exp2f(s0f[r] - mn);
      s1f[r] = __builtin_amdgcn_exp2f(s1f[r] - mn);
    }
    float sm[16];
#pragma unroll
    for (int r = 0; r < 16; ++r) sm[r] = s0f[r] + s1f[r];
#pragma unroll
    for (int w = 8; w; w >>= 1)
#pragma unroll
      for (int r = 0; r < w; ++r) sm[r] += sm[r + w];
    float sum = sm[0] + __shfl_xor(sm[0], 32, 64);
    if (defer) {
      l_run += sum;
    } else {
      float al = __builtin_amdgcn_exp2f(m_run - mn);
      l_run = l_run * al + sum;
      m_run = mn;
#pragma unroll
      for (int i = 0; i < 4; ++i)
#pragma unroll
        for (int j = 0; j < 16; ++j) Oc[i][j] *= al;
    }
#pragma unroll
    for (int m = 0; m < 8; ++m) {
      w0[m] = pk2(s0f[2 * m], s0f[2 * m + 1]);
      w1[m] = pk2(s1f[2 * m], s1f[2 * m + 1]);
    }
  };

  auto doPV = [&](int cur) {
    __builtin_amdgcn_s_setprio(1);
#pragma unroll
    for (int s = 0; s < 4; ++s) {
      const unsigned int* w = (s < 2) ? w0 : w1;
      const int lo4 = (s & 1) * 4;
      unsigned int x0 = __shfl_xor(w[lo4 + 2], 32, 64);
      unsigned int x1 = __shfl_xor(w[lo4 + 3], 32, 64);
      unsigned int y0 = __shfl_xor(w[lo4],     32, 64);
      unsigned int y1 = __shfl_xor(w[lo4 + 1], 32, 64);
      unsigned int fw[4];
      fw[0] = hh ? x0 : w[lo4];
      fw[1] = hh ? x1 : w[lo4 + 1];
      fw[2] = hh ? w[lo4 + 2] : y0;
      fw[3] = hh ? w[lo4 + 3] : y1;
      short8 pb = *(const short8*)fw;
#pragma unroll
      for (int dt = 0; dt < 4; ++dt) {
        int d = dt * 32 + l31;
        int byte = d * 128 + s * 32 + hh * 16;
        byte ^= (((d & 7) ^ ((d >> 3) & 7)) << 4);
        short8 vf = *(const short8*)((const char*)&Vt[cur][0] + byte);
        Oc[dt] = MFMA32(vf, pb, Oc[dt]);
      }
    }
    __builtin_amdgcn_s_setprio(0);
  };

  const int nt = (kvlen + 63) >> 6;
  short8 vp[2][2];

  issueK(qkv, h, 0, kvlen, woff, tid, &Kl[0][0]);
  if (nt > 1) issueK(qkv, h, 1, kvlen, woff, tid, &Kl[1][0]);
  loadV(qkv, h, 0, kvlen, woff, tid, vp);
  writeV(tid, vp, &Vt[0][0]);
  __syncthreads();

  f32x16 sp0, sp1;
  computeQK(0, 0, &sp0, &sp1);
  __syncthreads();

  for (int t = 0; t < nt - 1; ++t) {
    const int cur = t & 1;
    if (t + 2 < nt) issueK(qkv, h, t + 2, kvlen, woff, tid, &Kl[cur][0]);
    loadV(qkv, h, t + 1, kvlen, woff, tid, vp);

    f32x16 sc0, sc1;
    computeQK(t + 1, cur ^ 1, &sc0, &sc1);
    finishTile(sp0, sp1);
    writeV(tid, vp, &Vt[cur ^ 1][0]);
    doPV(cur);
    __syncthreads();
    sp0 = sc0; sp1 = sc1;
  }
  finishTile(sp0, sp1);
  doPV((nt - 1) & 1);

  const int qg = q0 + wave * 32 + l31;
  if (qg < chunk_end) {
    const float inv = 1.f / l_run;
    unsigned short* op = ob + (long)qg * 1536 + h * 128;
#pragma unroll
    for (int dt = 0; dt < 4; ++dt) {
#pragma unroll
      for (int gblk = 0; gblk < 4; ++gblk) {
        int d = dt * 32 + gblk * 8 + hh * 4;
        unsigned int u0 = pk2(Oc[dt][4 * gblk]     * inv, Oc[dt][4 * gblk + 1] * inv);
        unsigned int u1 = pk2(Oc[dt][4 * gblk + 2] * inv, Oc[dt][4 * gblk + 3] * inv);
        u32x2 uu; uu[0] = u0; uu[1] = u1;
        *(u32x2*)(op + d) = uu;
      }
    }
  }
}

// ---------------- launch ----------------
extern "C" void kernel_launch(void* const* d_in, const int* in_sizes, int n_in,
                              void* d_out, int out_size, void* d_ws, size_t ws_size,
                              hipStream_t stream)
{
  const float* x  = (const float*)d_in[0];
  const float* Wq = (const float*)d_in[1];
  const float* bq = (const float*)d_in[2];
  const float* Wk = (const float*)d_in[3];
  const float* bk = (const float*)d_in[4];
  const float* Wv = (const float*)d_in[5];
  const float* bv = (const float*)d_in[6];
  const float* Wo = (const float*)d_in[7];
  const float* bo = (const float*)d_in[8];
  const float* gq = (const float*)d_in[9];
  const float* gk = (const float*)d_in[10];
  const float* fc = (const float*)d_in[11];
  const float* fs = (const float*)d_in[12];

  // ws layout (107MB): xb padded to 7168 rows; obuf aliases xb (dead after gemm0)
  char* ws = (char*)d_ws;
  unsigned short* xb   = (unsigned short*)(ws);               // 7168x1536 bf16 = 22,020,096 B
  unsigned short* obuf = xb;                                  // 7040x1536 bf16 (after gemm0)
  unsigned short* wcat = (unsigned short*)(ws + 22020096);    // 14,155,776 B
  unsigned short* wob  = (unsigned short*)(ws + 36175872);    //  4,718,592 B
  float*          bcat = (float*)(ws + 40894464);             //     18,432 B
  unsigned short* qkv  = (unsigned short*)(ws + 40912896);    // 7168x4608 bf16 = 66,060,288 B

  cvt_f32_bf16<<<2048, 256, 0, stream>>>(x, xb, 10813440 / 4);
  cvt4_f32_bf16<<<dim3(576, 4), 256, 0, stream>>>(
      Wq, Wk, Wv, Wo,
      wcat, wcat + 2359296, wcat + 4718592, wob, 2359296 / 4);
  hipMemcpyAsync(bcat,        bq, 1536 * 4, hipMemcpyDeviceToDevice, stream);
  hipMemcpyAsync(bcat + 1536, bk, 1536 * 4, hipMemcpyDeviceToDevice, stream);
  hipMemcpyAsync(bcat + 3072, bv, 1536 * 4, hipMemcpyDeviceToDevice, stream);

  // QKV projection, 8-phase 256^2: [7168x4608] = xb . wcat^T + bcat
  gemm8<<<504, 512, 0, stream>>>(xb, wcat, bcat, qkv);

  const float qsc = (float)(1.4426950408889634 / sqrt(128.0));
  normrope<<<dim3(7040, 2), 256, 0, stream>>>(qkv, gq, gk, fc, fs, qsc);

  attn_kern<<<dim3(14, 4, 12), 256, 0, stream>>>(qkv, obuf);

  // output projection: d_out = obuf . Wo^T + bo (f32) ; nwg=660, q=82, r=4
  gemm_bt<<<660, 256, 0, stream>>>(obuf, wob, bo, (float*)d_out, 1536, 1536,
                                   12, 660 / 8, 660 % 8);
}